// Round 10
// baseline (178.632 us; speedup 1.0000x reference)
//
#include <hip/hip_runtime.h>
#include <hip/hip_bf16.h>

typedef __attribute__((ext_vector_type(8))) short bf16x8;
typedef __attribute__((ext_vector_type(4))) float f32x4;
using bf16 = __hip_bfloat16;

#define NTOK 4096
#define EPS_LN 1e-5f
#define QSCL 0.1803368801111244f  // 0.125 * log2(e): softmax in exp2 domain

enum { EPI_F32 = 0, EPI_QKV = 1, EPI_RELU_BF16 = 2 };

#define VM8 asm volatile("s_waitcnt vmcnt(8)" ::: "memory")
#define VM0 asm volatile("s_waitcnt vmcnt(0)" ::: "memory")
#define LGKM0 asm volatile("s_waitcnt lgkmcnt(0)" ::: "memory")
#define SCHED0 __builtin_amdgcn_sched_barrier(0)
#define NOVM
#define DSRO(dst, ad, off) \
  asm volatile("ds_read_b128 %0, %1 offset:" #off : "=v"(dst) : "v"(ad))

__device__ inline void gload_lds16(const void* g, void* l) {
  __builtin_amdgcn_global_load_lds(
      (const __attribute__((address_space(1))) char*)g,
      (__attribute__((address_space(3))) char*)l, 16, 0, 0);
}

__device__ inline unsigned ldsoff(const void* p) {
  return (unsigned)(size_t)(const __attribute__((address_space(3))) char*)p;
}

__device__ inline unsigned short f2bfu(float x) {
  bf16 h = __float2bfloat16(x);
  return __builtin_bit_cast(unsigned short, h);
}
__device__ inline bf16 to_bf16(float v) { return __float2bfloat16(v); }
__device__ inline bf16 to_bf16(bf16 v) { return v; }

// ---------------- prep kernels ----------------

__global__ __launch_bounds__(256) void cvt_bf16_kernel(const float* __restrict__ src,
                                                       bf16* __restrict__ dst, int n4) {
  int i = blockIdx.x * 256 + threadIdx.x;
  if (i >= n4) return;
  float4 v = ((const float4*)src)[i];
  ushort4 o;
  o.x = f2bfu(v.x); o.y = f2bfu(v.y); o.z = f2bfu(v.z); o.w = f2bfu(v.w);
  ((ushort4*)dst)[i] = o;
}

template <typename ST>
__global__ __launch_bounds__(256) void transpose_cvt(const ST* __restrict__ src,
                                                     bf16* __restrict__ dst, int R, int C) {
  __shared__ bf16 tile[32][33];
  int o = blockIdx.z;
  int r0 = blockIdx.y * 32, c0 = blockIdx.x * 32;
  int tx = threadIdx.x & 31, ty = threadIdx.x >> 5;
  const ST* s = src + (size_t)o * R * C;
  bf16* d = dst + (size_t)o * R * C;
#pragma unroll
  for (int i = 0; i < 32; i += 8)
    tile[ty + i][tx] = to_bf16(s[(size_t)(r0 + ty + i) * C + (c0 + tx)]);
  __syncthreads();
#pragma unroll
  for (int i = 0; i < 32; i += 8)
    d[(size_t)(c0 + ty + i) * R + (r0 + tx)] = tile[tx][ty + i];
}

__global__ __launch_bounds__(256) void pack_bias_kernel(const float* __restrict__ bq,
                                                        const float* __restrict__ bk,
                                                        const float* __restrict__ bv,
                                                        float* __restrict__ out) {
  int i = blockIdx.x * 256 + threadIdx.x;
  if (i >= 3072) return;
  out[i] = (i < 1024) ? bq[i] : (i < 2048 ? bk[i - 1024] : bv[i - 2048]);
}

// ---------------- GEMM: 128x128 tile, dbuf, 4 waves, 2 blocks/CU ----------
// (unchanged from R9 — proven)

#define STG(KOFF, DD) { _Pragma("unroll") for (int q = 0; q < 4; ++q) { \
    gload_lds16(gA0 + (KOFF) + (size_t)(q * 32) * lda2, \
                sAb + (DD) * 16384 + q * 4096 + w * 1024); \
    gload_lds16(gB0 + (KOFF) + (size_t)(q * 32) * ldb2, \
                sBb + (DD) * 16384 + q * 4096 + w * 1024); } }

#define TILE(OFFLIT, STG_, VMS) { \
  _Pragma("unroll") for (int i = 0; i < 4; ++i) { \
    DSRO(a[i][0], adA[i][0], OFFLIT); \
    DSRO(a[i][1], adA[i][1], OFFLIT); \
  } \
  _Pragma("unroll") for (int j = 0; j < 4; ++j) { \
    DSRO(b[j][0], adB[j][0], OFFLIT); \
    DSRO(b[j][1], adB[j][1], OFFLIT); \
  } \
  LGKM0; SCHED0; \
  __builtin_amdgcn_s_barrier(); \
  STG_; \
  __builtin_amdgcn_s_setprio(1); \
  _Pragma("unroll") for (int i = 0; i < 4; ++i) \
  _Pragma("unroll") for (int j = 0; j < 4; ++j) \
  _Pragma("unroll") for (int kk = 0; kk < 2; ++kk) \
    acc[i][j] = __builtin_amdgcn_mfma_f32_16x16x32_bf16( \
        a[i][kk], b[j][kk], acc[i][j], 0, 0, 0); \
  __builtin_amdgcn_s_setprio(0); \
  VMS; \
  __builtin_amdgcn_s_barrier(); }

__global__ __launch_bounds__(256, 2) void gemm128(
    const bf16* __restrict__ A, int lda,
    const bf16* __restrict__ Bt, int ldb,
    int M, int N, int K,  // K % 128 == 0
    int nbm, int nbn,
    const float* __restrict__ bias,
    float* __restrict__ Cf, bf16* __restrict__ Cb,
    bf16* __restrict__ Qd, bf16* __restrict__ Kd, bf16* __restrict__ Vd,
    int mode) {
  __shared__ bf16 sA[2][128][64];
  __shared__ bf16 sB[2][128][64];
  const int nwg = nbm * nbn;
  const int orig = blockIdx.x;
  const int wgid = (orig % 8) * (nwg / 8) + orig / 8;  // nwg % 8 == 0
  const int bm = wgid / nbn, bn = wgid % nbn;
  const int tid = threadIdx.x;
  const int w = tid >> 6, lane = tid & 63;
  const int wm = w >> 1, wn = w & 1;
  const int ri = lane & 15, kg = lane >> 4;
  const bf16* Ab = A + (size_t)bm * 128 * lda;
  const bf16* Bb = Bt + (size_t)bn * 128 * ldb;
  const int NT = K / 64;
  const size_t lda2 = (size_t)lda * 2, ldb2 = (size_t)ldb * 2;
  char* sAb = (char*)&sA[0][0][0];
  char* sBb = (char*)&sB[0][0][0];

  unsigned adA[4][2], adB[4][2];
  const unsigned sA0 = ldsoff(sAb), sB0 = ldsoff(sBb);
#pragma unroll
  for (int i = 0; i < 4; ++i) {
    int row = wm * 64 + i * 16 + ri;
    unsigned swz = (unsigned)((row & 7) << 4);
    adA[i][0] = sA0 + row * 128 + ((kg * 16) ^ swz);
    adA[i][1] = sA0 + row * 128 + ((64 + kg * 16) ^ swz);
  }
#pragma unroll
  for (int j = 0; j < 4; ++j) {
    int row = wn * 64 + j * 16 + ri;
    unsigned swz = (unsigned)((row & 7) << 4);
    adB[j][0] = sB0 + row * 128 + ((kg * 16) ^ swz);
    adB[j][1] = sB0 + row * 128 + ((64 + kg * 16) ^ swz);
  }

  const int r0 = tid >> 3;
  const int cb0 = ((tid & 7) * 16) ^ ((r0 & 7) << 4);
  const char* gA0 = (const char*)Ab + (size_t)r0 * lda2 + cb0;
  const char* gB0 = (const char*)Bb + (size_t)r0 * ldb2 + cb0;

  f32x4 acc[4][4] = {};
  bf16x8 a[4][2], b[4][2];

  STG(0, 0) STG(128, 1)
  VM8;
  __builtin_amdgcn_s_barrier();

  const int niter = NT / 2 - 1;
  for (int it = 0; it < niter; ++it) {
    TILE(0,     STG(256, 0), VM8)
    TILE(16384, STG(384, 1), VM8)
    gA0 += 256; gB0 += 256;
  }
  TILE(0,     , VM0)
  TILE(16384, , NOVM)

  const int colbase = bn * 128 + wn * 64 + ri;
  float bv4[4];
#pragma unroll
  for (int nf = 0; nf < 4; ++nf)
    bv4[nf] = bias ? bias[colbase + nf * 16] : 0.f;

  if (mode == EPI_QKV) {
    int col0 = bn * 128 + wn * 64;
    int which = col0 >> 10, hh = (col0 >> 6) & 15;
    bf16* dst = (which == 0) ? Qd : (which == 1) ? Kd : Vd;
    float scl = (which == 0) ? QSCL : 1.0f;
#pragma unroll
    for (int mf = 0; mf < 4; ++mf)
#pragma unroll
      for (int r = 0; r < 4; ++r) {
        int row = bm * 128 + wm * 64 + mf * 16 + kg * 4 + r;
        int b2 = row >> 10, s = row & 1023;
        bf16* o = dst + (((size_t)(b2 * 16 + hh)) * 1024 + s) * 64;
#pragma unroll
        for (int nf = 0; nf < 4; ++nf)
          o[nf * 16 + ri] = __float2bfloat16((acc[mf][nf][r] + bv4[nf]) * scl);
      }
  } else if (mode == EPI_F32) {
#pragma unroll
    for (int mf = 0; mf < 4; ++mf)
#pragma unroll
      for (int r = 0; r < 4; ++r) {
        int row = bm * 128 + wm * 64 + mf * 16 + kg * 4 + r;
        float* o = Cf + (size_t)row * N + colbase;
#pragma unroll
        for (int nf = 0; nf < 4; ++nf) o[nf * 16] = acc[mf][nf][r] + bv4[nf];
      }
  } else {  // EPI_RELU_BF16
#pragma unroll
    for (int mf = 0; mf < 4; ++mf)
#pragma unroll
      for (int r = 0; r < 4; ++r) {
        int row = bm * 128 + wm * 64 + mf * 16 + kg * 4 + r;
        bf16* o = Cb + (size_t)row * N + colbase;
#pragma unroll
        for (int nf = 0; nf < 4; ++nf) {
          float v = acc[mf][nf][r] + bv4[nf];
          o[nf * 16] = __float2bfloat16(v > 0.f ? v : 0.f);
        }
      }
  }
}

// ---------------- flash attention: swapped-QK, 32 q-rows/wave ----------------
// grid 512 = 64 bh * 8 q-blocks (XCD-grouped). 4 waves x 32 q-rows (2 frags).
// K-fragments are query-independent: read once, both frags' QK MFMAs issued
// back-to-back (frag1 drains under frag0's softmax). Staging & barriers per
// unit work halved vs 16 rows/wave.
__global__ __launch_bounds__(256, 3) void attn_kernel(
    const bf16* __restrict__ Qb, const bf16* __restrict__ Kb,
    const bf16* __restrict__ Vs, bf16* __restrict__ Ob) {
  __shared__ bf16 KV[2][2][64][64];  // [dbuf][0=K rows=key | 1=V^T rows=d]
  __shared__ bf16 Ps[4][16][64];     // per-wave P [query][key], swizzled
  const int orig = blockIdx.x;
  const int blk = (orig & 7) * 64 + (orig >> 3);  // 512 % 8 == 0
  const int bh = blk >> 3, qb = blk & 7;
  const int bb = bh >> 4, hh = bh & 15;
  const int tid = threadIdx.x, w = tid >> 6, lane = tid & 63;
  const int ri = lane & 15, kg = lane >> 4, r8 = lane >> 3;
  const int cb = ((lane & 7) * 16) ^ ((r8 & 7) << 4);  // pre-swizzled source
  const unsigned rsw = (unsigned)((ri & 7) << 4);
  const bf16* qp = Qb + (size_t)bh * 65536;
  const bf16* kp = Kb + (size_t)bh * 65536;
  const bf16* vp = Vs + (size_t)bh * 65536;
  const int q0 = qb * 128 + w * 32;
  const int c0 = w * 2, c1 = c0 + 1;

  unsigned offk0 = (unsigned)((kg * 16) ^ (int)rsw);
  unsigned offk1 = (unsigned)((64 + kg * 16) ^ (int)rsw);
  unsigned adF[4][2];
  const unsigned kv0 = ldsoff(&KV[0][0][0][0]);
#pragma unroll
  for (int n = 0; n < 4; ++n) {
    unsigned row = (unsigned)((n * 16 + ri) * 128);
    adF[n][0] = kv0 + row + offk0;
    adF[n][1] = kv0 + row + offk1;
  }
  const unsigned ps0 = ldsoff(&Ps[0][0][0]) + (unsigned)(w * 2048 + ri * 128);
  unsigned adPr[2] = {ps0 + offk0, ps0 + offk1};
  char* pwb = (char*)&Ps[0][0][0] + w * 2048 + ri * 128;

  bf16x8 qf[2][2];
#pragma unroll
  for (int f = 0; f < 2; ++f) {
    qf[f][0] = *(const bf16x8*)(qp + (size_t)(q0 + f * 16 + ri) * 64 + kg * 8);
    qf[f][1] = *(const bf16x8*)(qp + (size_t)(q0 + f * 16 + ri) * 64 + 32 + kg * 8);
  }

  f32x4 oacc[2][4] = {};
  float mrun[2] = {-1e30f, -1e30f}, lrun[2] = {0.f, 0.f};

#define ASTAGE(T, D) { \
    gload_lds16((const char*)(kp + (size_t)((T) * 64 + c0 * 8 + r8) * 64) + cb, \
                (char*)KV + (D) * 16384 + c0 * 1024); \
    gload_lds16((const char*)(kp + (size_t)((T) * 64 + c1 * 8 + r8) * 64) + cb, \
                (char*)KV + (D) * 16384 + c1 * 1024); \
    gload_lds16((const char*)(vp + (size_t)(c0 * 8 + r8) * 1024 + (T) * 64) + cb, \
                (char*)KV + (D) * 16384 + 8192 + c0 * 1024); \
    gload_lds16((const char*)(vp + (size_t)(c1 * 8 + r8) * 1024 + (T) * 64) + cb, \
                (char*)KV + (D) * 16384 + 8192 + c1 * 1024); }

  ASTAGE(0, 0);
  VM0;
  __syncthreads();

  for (int t = 0; t < 16; ++t) {
    const int cur = t & 1;
    if (t < 15) ASTAGE(t + 1, cur ^ 1);  // flies across the whole tile
    const unsigned bo = (unsigned)(cur * 16384);

    // K fragments: shared by both q-frags — read once
    bf16x8 kf[2][4];
#pragma unroll
    for (int n = 0; n < 4; ++n) {
      DSRO(kf[0][n], adF[n][0] + bo, 0);
      DSRO(kf[1][n], adF[n][1] + bo, 0);
    }
    LGKM0; SCHED0;
    f32x4 sac[2][4] = {};
#pragma unroll
    for (int f = 0; f < 2; ++f)
#pragma unroll
      for (int n = 0; n < 4; ++n) {
        sac[f][n] = __builtin_amdgcn_mfma_f32_16x16x32_bf16(kf[0][n], qf[f][0], sac[f][n], 0, 0, 0);
        sac[f][n] = __builtin_amdgcn_mfma_f32_16x16x32_bf16(kf[1][n], qf[f][1], sac[f][n], 0, 0, 0);
      }

#pragma unroll
    for (int f = 0; f < 2; ++f) {
      // lane-local softmax for query ri (16 scores: keys n*16+kg*4+r)
      float mx[4];
#pragma unroll
      for (int n = 0; n < 4; ++n)
        mx[n] = fmaxf(fmaxf(sac[f][n][0], sac[f][n][1]), fmaxf(sac[f][n][2], sac[f][n][3]));
      float mt = fmaxf(fmaxf(mx[0], mx[1]), fmaxf(mx[2], mx[3]));
      mt = fmaxf(mt, __shfl_xor(mt, 16));
      mt = fmaxf(mt, __shfl_xor(mt, 32));
      if (!__all(mt - mrun[f] <= 8.f)) {  // defer-max (T13)
        float mnew = fmaxf(mrun[f], mt);
        float corr = exp2f(mrun[f] - mnew);
        mrun[f] = mnew;
        lrun[f] *= corr;
        float cr[4];
#pragma unroll
        for (int r = 0; r < 4; ++r) cr[r] = __shfl(corr, kg * 4 + r);
#pragma unroll
        for (int n = 0; n < 4; ++n) {
          oacc[f][n][0] *= cr[0]; oacc[f][n][1] *= cr[1];
          oacc[f][n][2] *= cr[2]; oacc[f][n][3] *= cr[3];
        }
      }
      float p[4][4];
      float su[4];
#pragma unroll
      for (int n = 0; n < 4; ++n) {
        p[n][0] = exp2f(sac[f][n][0] - mrun[f]); p[n][1] = exp2f(sac[f][n][1] - mrun[f]);
        p[n][2] = exp2f(sac[f][n][2] - mrun[f]); p[n][3] = exp2f(sac[f][n][3] - mrun[f]);
        su[n] = (p[n][0] + p[n][1]) + (p[n][2] + p[n][3]);
      }
      float sum = (su[0] + su[1]) + (su[2] + su[3]);
      sum += __shfl_xor(sum, 16);
      sum += __shfl_xor(sum, 32);
      lrun[f] += sum;
#pragma unroll
      for (int n = 0; n < 4; ++n) {
        ushort4 pk;
        pk.x = f2bfu(p[n][0]); pk.y = f2bfu(p[n][1]);
        pk.z = f2bfu(p[n][2]); pk.w = f2bfu(p[n][3]);
        *(ushort4*)(pwb + (((n * 32 + kg * 8)) ^ (int)rsw)) = pk;
      }
      LGKM0;

      bf16x8 pf[2], vf[2][4];
      DSRO(pf[0], adPr[0], 0);
      DSRO(pf[1], adPr[1], 0);
#pragma unroll
      for (int n = 0; n < 4; ++n) {
        DSRO(vf[0][n], adF[n][0] + bo, 8192);
        DSRO(vf[1][n], adF[n][1] + bo, 8192);
      }
      LGKM0; SCHED0;
#pragma unroll
      for (int n = 0; n < 4; ++n) {
        oacc[f][n] = __builtin_amdgcn_mfma_f32_16x16x32_bf16(pf[0], vf[0][n], oacc[f][n], 0, 0, 0);
        oacc[f][n] = __builtin_amdgcn_mfma_f32_16x16x32_bf16(pf[1], vf[1][n], oacc[f][n], 0, 0, 0);
      }
    }
    if (t < 15) {
      VM0;
      __syncthreads();
    }
  }

#pragma unroll
  for (int f = 0; f < 2; ++f) {
    float inv = 1.f / lrun[f];
    float ivr[4];
#pragma unroll
    for (int r = 0; r < 4; ++r) ivr[r] = __shfl(inv, kg * 4 + r);
#pragma unroll
    for (int r = 0; r < 4; ++r) {
      int s = q0 + f * 16 + kg * 4 + r;
      size_t base = ((size_t)(bb * 1024 + s)) * 1024 + hh * 64;
#pragma unroll
      for (int n = 0; n < 4; ++n)
        Ob[base + n * 16 + ri] = __float2bfloat16(oacc[f][n][r] * ivr[r]);
    }
  }
#undef ASTAGE
}

// ---------------- fused residual + LayerNorm ----------------
__global__ __launch_bounds__(256) void ln_kernel(
    const float* __restrict__ a, const float* __restrict__ b,
    const float* __restrict__ gamma, const float* __restrict__ beta,
    float* __restrict__ out_f32, bf16* __restrict__ out_bf16) {
  int row = blockIdx.x;
  int tid = threadIdx.x;
  float4 av = ((const float4*)(a + (size_t)row * 1024))[tid];
  float4 bv = ((const float4*)(b + (size_t)row * 1024))[tid];
  float4 z;
  z.x = av.x + bv.x; z.y = av.y + bv.y; z.z = av.z + bv.z; z.w = av.w + bv.w;
  float s = z.x + z.y + z.z + z.w;
  float ss = z.x * z.x + z.y * z.y + z.z * z.z + z.w * z.w;
#pragma unroll
  for (int o = 32; o >= 1; o >>= 1) { s += __shfl_xor(s, o); ss += __shfl_xor(ss, o); }
  __shared__ float red[8];
  int wid = tid >> 6;
  if ((tid & 63) == 0) { red[wid] = s; red[4 + wid] = ss; }
  __syncthreads();
  s = red[0] + red[1] + red[2] + red[3];
  ss = red[4] + red[5] + red[6] + red[7];
  float mean = s * (1.f / 1024.f);
  float var = ss * (1.f / 1024.f) - mean * mean;
  var = var > 0.f ? var : 0.f;
  float inv = 1.f / (sqrtf(var) + EPS_LN);
  float4 g = ((const float4*)gamma)[tid];
  float4 be = ((const float4*)beta)[tid];
  float4 y;
  y.x = (z.x - mean) * inv * g.x + be.x;
  y.y = (z.y - mean) * inv * g.y + be.y;
  y.z = (z.z - mean) * inv * g.z + be.z;
  y.w = (z.w - mean) * inv * g.w + be.w;
  ((float4*)(out_f32 + (size_t)row * 1024))[tid] = y;
  if (out_bf16) {
    ushort4 o;
    o.x = f2bfu(y.x); o.y = f2bfu(y.y); o.z = f2bfu(y.z); o.w = f2bfu(y.w);
    ((ushort4*)(out_bf16 + (size_t)row * 1024))[tid] = o;
  }
}

// ---------------- launch ----------------
extern "C" void kernel_launch(void* const* d_in, const int* in_sizes, int n_in,
                              void* d_out, int out_size, void* d_ws, size_t ws_size,
                              hipStream_t stream) {
  const float* x = (const float*)d_in[0];
  const float* wq = (const float*)d_in[1];
  const float* bq = (const float*)d_in[2];
  const float* wk = (const float*)d_in[3];
  const float* bk = (const float*)d_in[4];
  const float* wv = (const float*)d_in[5];
  const float* bv = (const float*)d_in[6];
  const float* wo_w = (const float*)d_in[7];
  const float* wo_b = (const float*)d_in[8];
  const float* g1 = (const float*)d_in[9];
  const float* b1 = (const float*)d_in[10];
  const float* ff1w = (const float*)d_in[11];
  const float* ff1b = (const float*)d_in[12];
  const float* ff2w = (const float*)d_in[13];
  const float* ff2b = (const float*)d_in[14];
  const float* g2 = (const float*)d_in[15];
  const float* b2 = (const float*)d_in[16];

  char* ws = (char*)d_ws;
  size_t off = 0;
  auto alloc = [&](size_t bytes) {
    char* p = ws + off;
    off += (bytes + 255) & ~(size_t)255;
    return p;
  };
  bf16* xb = (bf16*)alloc((size_t)NTOK * 1024 * 2);
  bf16* wqkvt = (bf16*)alloc((size_t)3072 * 1024 * 2);
  bf16* wot = (bf16*)alloc((size_t)1024 * 1024 * 2);
  bf16* ff1t = (bf16*)alloc((size_t)2048 * 1024 * 2);
  bf16* ff2t = (bf16*)alloc((size_t)1024 * 2048 * 2);
  float* qkvbias = (float*)alloc(3072 * 4);
  bf16* qbuf = (bf16*)alloc((size_t)64 * 1024 * 64 * 2);
  bf16* kbuf = (bf16*)alloc((size_t)64 * 1024 * 64 * 2);
  bf16* vbuf = (bf16*)alloc((size_t)64 * 1024 * 64 * 2);
  bf16* vtb = (bf16*)alloc((size_t)64 * 64 * 1024 * 2);
  bf16* attnb = (bf16*)alloc((size_t)NTOK * 1024 * 2);
  float* proj = (float*)alloc((size_t)NTOK * 1024 * 4);
  bf16* hb = (bf16*)alloc((size_t)NTOK * 1024 * 2);
  bf16* ff1o = qbuf;            // reuse q+k region (dead after attention)
  float* hbuf = (float*)d_out;  // f32 h scratch (fully rewritten by LN2)

  // prep
  cvt_bf16_kernel<<<(NTOK * 1024 / 4 + 255) / 256, 256, 0, stream>>>(x, xb, NTOK * 1024 / 4);
  transpose_cvt<float><<<dim3(2, 32, 16), 256, 0, stream>>>(wq, wqkvt, 1024, 64);
  transpose_cvt<float><<<dim3(2, 32, 16), 256, 0, stream>>>(wk, wqkvt + 1024 * 1024, 1024, 64);
  transpose_cvt<float><<<dim3(2, 32, 16), 256, 0, stream>>>(wv, wqkvt + 2 * 1024 * 1024, 1024, 64);
  transpose_cvt<float><<<dim3(32, 32, 1), 256, 0, stream>>>(wo_w, wot, 1024, 1024);
  transpose_cvt<float><<<dim3(64, 32, 1), 256, 0, stream>>>(ff1w, ff1t, 1024, 2048);
  transpose_cvt<float><<<dim3(32, 64, 1), 256, 0, stream>>>(ff2w, ff2t, 2048, 1024);
  pack_bias_kernel<<<12, 256, 0, stream>>>(bq, bk, bv, qkvbias);

  // QKV: [4096,1024] x [3072,1024]^T, 768 blocks (3/CU)
  gemm128<<<768, 256, 0, stream>>>(xb, 1024, wqkvt, 1024, 4096, 3072, 1024,
                                   32, 24, qkvbias,
                                   nullptr, nullptr, qbuf, kbuf, vbuf, EPI_QKV);
  // V -> V^T per (b,h)
  transpose_cvt<bf16><<<dim3(2, 32, 64), 256, 0, stream>>>(vbuf, vtb, 1024, 64);
  // attention: 512 blocks x 4 waves, 32 q-rows/wave
  attn_kernel<<<dim3(512), 256, 0, stream>>>(qbuf, kbuf, vtb, attnb);
  // output projection: 256 blocks
  gemm128<<<256, 256, 0, stream>>>(attnb, 1024, wot, 1024, 4096, 1024, 1024,
                                   32, 8, wo_b,
                                   proj, nullptr, nullptr, nullptr, nullptr, EPI_F32);
  // LN1: h = LN(x + proj)
  ln_kernel<<<4096, 256, 0, stream>>>(x, proj, g1, b1, hbuf, hb);
  // FF1 + ReLU: 512 blocks
  gemm128<<<512, 256, 0, stream>>>(hb, 1024, ff1t, 1024, 4096, 2048, 1024,
                                   32, 16, ff1b,
                                   nullptr, ff1o, nullptr, nullptr, nullptr, EPI_RELU_BF16);
  // FF2: 256 blocks, K=2048
  gemm128<<<256, 256, 0, stream>>>(ff1o, 2048, ff2t, 2048, 4096, 1024, 2048,
                                   32, 8, ff2b,
                                   proj, nullptr, nullptr, nullptr, nullptr, EPI_F32);
  // LN2 -> d_out
  ln_kernel<<<4096, 256, 0, stream>>>(hbuf, proj, g2, b2, (float*)d_out, nullptr);
}

// Round 11
// 175.291 us; speedup vs baseline: 1.0191x; 1.0191x over previous
//
#include <hip/hip_runtime.h>
#include <hip/hip_bf16.h>

typedef __attribute__((ext_vector_type(8))) short bf16x8;
typedef __attribute__((ext_vector_type(4))) float f32x4;
using bf16 = __hip_bfloat16;

#define NTOK 4096
#define EPS_LN 1e-5f
#define QSCL 0.1803368801111244f  // 0.125 * log2(e): softmax in exp2 domain

enum { EPI_F32 = 0, EPI_QKV = 1, EPI_RELU_BF16 = 2 };

#define VM8 asm volatile("s_waitcnt vmcnt(8)" ::: "memory")
#define VM0 asm volatile("s_waitcnt vmcnt(0)" ::: "memory")
#define LGKM0 asm volatile("s_waitcnt lgkmcnt(0)" ::: "memory")
#define SCHED0 __builtin_amdgcn_sched_barrier(0)
#define NOVM
#define DSRO(dst, ad, off) \
  asm volatile("ds_read_b128 %0, %1 offset:" #off : "=v"(dst) : "v"(ad))

__device__ inline void gload_lds16(const void* g, void* l) {
  __builtin_amdgcn_global_load_lds(
      (const __attribute__((address_space(1))) char*)g,
      (__attribute__((address_space(3))) char*)l, 16, 0, 0);
}

__device__ inline unsigned ldsoff(const void* p) {
  return (unsigned)(size_t)(const __attribute__((address_space(3))) char*)p;
}

__device__ inline unsigned short f2bfu(float x) {
  bf16 h = __float2bfloat16(x);
  return __builtin_bit_cast(unsigned short, h);
}
__device__ inline bf16 to_bf16(float v) { return __float2bfloat16(v); }
__device__ inline bf16 to_bf16(bf16 v) { return v; }

// ---------------- prep kernels ----------------

__global__ __launch_bounds__(256) void cvt_bf16_kernel(const float* __restrict__ src,
                                                       bf16* __restrict__ dst, int n4) {
  int i = blockIdx.x * 256 + threadIdx.x;
  if (i >= n4) return;
  float4 v = ((const float4*)src)[i];
  ushort4 o;
  o.x = f2bfu(v.x); o.y = f2bfu(v.y); o.z = f2bfu(v.z); o.w = f2bfu(v.w);
  ((ushort4*)dst)[i] = o;
}

template <typename ST>
__global__ __launch_bounds__(256) void transpose_cvt(const ST* __restrict__ src,
                                                     bf16* __restrict__ dst, int R, int C) {
  __shared__ bf16 tile[32][33];
  int o = blockIdx.z;
  int r0 = blockIdx.y * 32, c0 = blockIdx.x * 32;
  int tx = threadIdx.x & 31, ty = threadIdx.x >> 5;
  const ST* s = src + (size_t)o * R * C;
  bf16* d = dst + (size_t)o * R * C;
#pragma unroll
  for (int i = 0; i < 32; i += 8)
    tile[ty + i][tx] = to_bf16(s[(size_t)(r0 + ty + i) * C + (c0 + tx)]);
  __syncthreads();
#pragma unroll
  for (int i = 0; i < 32; i += 8)
    d[(size_t)(c0 + ty + i) * R + (r0 + tx)] = tile[tx][ty + i];
}

__global__ __launch_bounds__(256) void pack_bias_kernel(const float* __restrict__ bq,
                                                        const float* __restrict__ bk,
                                                        const float* __restrict__ bv,
                                                        float* __restrict__ out) {
  int i = blockIdx.x * 256 + threadIdx.x;
  if (i >= 3072) return;
  out[i] = (i < 1024) ? bq[i] : (i < 2048 ? bk[i - 1024] : bv[i - 2048]);
}

// ---------------- GEMM: 128x128 tile, dbuf, 4 waves, 2 blocks/CU ----------
// (unchanged from R9 — proven)

#define STG(KOFF, DD) { _Pragma("unroll") for (int q = 0; q < 4; ++q) { \
    gload_lds16(gA0 + (KOFF) + (size_t)(q * 32) * lda2, \
                sAb + (DD) * 16384 + q * 4096 + w * 1024); \
    gload_lds16(gB0 + (KOFF) + (size_t)(q * 32) * ldb2, \
                sBb + (DD) * 16384 + q * 4096 + w * 1024); } }

#define TILE(OFFLIT, STG_, VMS) { \
  _Pragma("unroll") for (int i = 0; i < 4; ++i) { \
    DSRO(a[i][0], adA[i][0], OFFLIT); \
    DSRO(a[i][1], adA[i][1], OFFLIT); \
  } \
  _Pragma("unroll") for (int j = 0; j < 4; ++j) { \
    DSRO(b[j][0], adB[j][0], OFFLIT); \
    DSRO(b[j][1], adB[j][1], OFFLIT); \
  } \
  LGKM0; SCHED0; \
  __builtin_amdgcn_s_barrier(); \
  STG_; \
  __builtin_amdgcn_s_setprio(1); \
  _Pragma("unroll") for (int i = 0; i < 4; ++i) \
  _Pragma("unroll") for (int j = 0; j < 4; ++j) \
  _Pragma("unroll") for (int kk = 0; kk < 2; ++kk) \
    acc[i][j] = __builtin_amdgcn_mfma_f32_16x16x32_bf16( \
        a[i][kk], b[j][kk], acc[i][j], 0, 0, 0); \
  __builtin_amdgcn_s_setprio(0); \
  VMS; \
  __builtin_amdgcn_s_barrier(); }

__global__ __launch_bounds__(256, 2) void gemm128(
    const bf16* __restrict__ A, int lda,
    const bf16* __restrict__ Bt, int ldb,
    int M, int N, int K,  // K % 128 == 0
    int nbm, int nbn,
    const float* __restrict__ bias,
    float* __restrict__ Cf, bf16* __restrict__ Cb,
    bf16* __restrict__ Qd, bf16* __restrict__ Kd, bf16* __restrict__ Vd,
    int mode) {
  __shared__ bf16 sA[2][128][64];
  __shared__ bf16 sB[2][128][64];
  const int nwg = nbm * nbn;
  const int orig = blockIdx.x;
  const int wgid = (orig % 8) * (nwg / 8) + orig / 8;  // nwg % 8 == 0
  const int bm = wgid / nbn, bn = wgid % nbn;
  const int tid = threadIdx.x;
  const int w = tid >> 6, lane = tid & 63;
  const int wm = w >> 1, wn = w & 1;
  const int ri = lane & 15, kg = lane >> 4;
  const bf16* Ab = A + (size_t)bm * 128 * lda;
  const bf16* Bb = Bt + (size_t)bn * 128 * ldb;
  const int NT = K / 64;
  const size_t lda2 = (size_t)lda * 2, ldb2 = (size_t)ldb * 2;
  char* sAb = (char*)&sA[0][0][0];
  char* sBb = (char*)&sB[0][0][0];

  unsigned adA[4][2], adB[4][2];
  const unsigned sA0 = ldsoff(sAb), sB0 = ldsoff(sBb);
#pragma unroll
  for (int i = 0; i < 4; ++i) {
    int row = wm * 64 + i * 16 + ri;
    unsigned swz = (unsigned)((row & 7) << 4);
    adA[i][0] = sA0 + row * 128 + ((kg * 16) ^ swz);
    adA[i][1] = sA0 + row * 128 + ((64 + kg * 16) ^ swz);
  }
#pragma unroll
  for (int j = 0; j < 4; ++j) {
    int row = wn * 64 + j * 16 + ri;
    unsigned swz = (unsigned)((row & 7) << 4);
    adB[j][0] = sB0 + row * 128 + ((kg * 16) ^ swz);
    adB[j][1] = sB0 + row * 128 + ((64 + kg * 16) ^ swz);
  }

  const int r0 = tid >> 3;
  const int cb0 = ((tid & 7) * 16) ^ ((r0 & 7) << 4);
  const char* gA0 = (const char*)Ab + (size_t)r0 * lda2 + cb0;
  const char* gB0 = (const char*)Bb + (size_t)r0 * ldb2 + cb0;

  f32x4 acc[4][4] = {};
  bf16x8 a[4][2], b[4][2];

  STG(0, 0) STG(128, 1)
  VM8;
  __builtin_amdgcn_s_barrier();

  const int niter = NT / 2 - 1;
  for (int it = 0; it < niter; ++it) {
    TILE(0,     STG(256, 0), VM8)
    TILE(16384, STG(384, 1), VM8)
    gA0 += 256; gB0 += 256;
  }
  TILE(0,     , VM0)
  TILE(16384, , NOVM)

  const int colbase = bn * 128 + wn * 64 + ri;
  float bv4[4];
#pragma unroll
  for (int nf = 0; nf < 4; ++nf)
    bv4[nf] = bias ? bias[colbase + nf * 16] : 0.f;

  if (mode == EPI_QKV) {
    int col0 = bn * 128 + wn * 64;
    int which = col0 >> 10, hh = (col0 >> 6) & 15;
    bf16* dst = (which == 0) ? Qd : (which == 1) ? Kd : Vd;
    float scl = (which == 0) ? QSCL : 1.0f;
#pragma unroll
    for (int mf = 0; mf < 4; ++mf)
#pragma unroll
      for (int r = 0; r < 4; ++r) {
        int row = bm * 128 + wm * 64 + mf * 16 + kg * 4 + r;
        int b2 = row >> 10, s = row & 1023;
        bf16* o = dst + (((size_t)(b2 * 16 + hh)) * 1024 + s) * 64;
#pragma unroll
        for (int nf = 0; nf < 4; ++nf)
          o[nf * 16 + ri] = __float2bfloat16((acc[mf][nf][r] + bv4[nf]) * scl);
      }
  } else if (mode == EPI_F32) {
#pragma unroll
    for (int mf = 0; mf < 4; ++mf)
#pragma unroll
      for (int r = 0; r < 4; ++r) {
        int row = bm * 128 + wm * 64 + mf * 16 + kg * 4 + r;
        float* o = Cf + (size_t)row * N + colbase;
#pragma unroll
        for (int nf = 0; nf < 4; ++nf) o[nf * 16] = acc[mf][nf][r] + bv4[nf];
      }
  } else {  // EPI_RELU_BF16
#pragma unroll
    for (int mf = 0; mf < 4; ++mf)
#pragma unroll
      for (int r = 0; r < 4; ++r) {
        int row = bm * 128 + wm * 64 + mf * 16 + kg * 4 + r;
        bf16* o = Cb + (size_t)row * N + colbase;
#pragma unroll
        for (int nf = 0; nf < 4; ++nf) {
          float v = acc[mf][nf][r] + bv4[nf];
          o[nf * 16] = __float2bfloat16(v > 0.f ? v : 0.f);
        }
      }
  }
}

// ---------------- flash attention: swapped-QK, MFMA l-sum, lazy max ----------
// grid 1024 = 64 bh * 16 q-tiles (R9 geometry, 4 blk/CU). 4 waves x 16 q-rows.
// l-sum rides the matrix pipe: lacc = mfma(P, ones, lacc) (B = const ones,
// no LDS); rescale multiplies lacc like oacc; final 1/l needs no shfl.
// Lazy max: defer-guard uses lane-local 16-key max; cross-lane max shfls run
// only on the (rare) update path. Non-update bound: p <= 2^8 (THR=8, as T13).
__global__ __launch_bounds__(256, 4) void attn_kernel(
    const bf16* __restrict__ Qb, const bf16* __restrict__ Kb,
    const bf16* __restrict__ Vs, bf16* __restrict__ Ob) {
  __shared__ bf16 KV[2][2][64][64];  // [dbuf][0=K rows=key | 1=V^T rows=d]
  __shared__ bf16 Ps[4][16][64];     // per-wave P [query][key], swizzled
  const int orig = blockIdx.x;
  const int blk = (orig & 7) * 128 + (orig >> 3);  // 1024 % 8 == 0
  const int bh = blk >> 4, qt = blk & 15;
  const int bb = bh >> 4, hh = bh & 15;
  const int tid = threadIdx.x, w = tid >> 6, lane = tid & 63;
  const int ri = lane & 15, kg = lane >> 4, r8 = lane >> 3;
  const int cb = ((lane & 7) * 16) ^ ((r8 & 7) << 4);  // pre-swizzled source
  const unsigned rsw = (unsigned)((ri & 7) << 4);
  const bf16* qp = Qb + (size_t)bh * 65536;
  const bf16* kp = Kb + (size_t)bh * 65536;
  const bf16* vp = Vs + (size_t)bh * 65536;
  const int q0 = qt * 64 + w * 16;
  const int c0 = w * 2, c1 = c0 + 1;

  unsigned offk0 = (unsigned)((kg * 16) ^ (int)rsw);
  unsigned offk1 = (unsigned)((64 + kg * 16) ^ (int)rsw);
  unsigned adF[4][2];
  const unsigned kv0 = ldsoff(&KV[0][0][0][0]);
#pragma unroll
  for (int n = 0; n < 4; ++n) {
    unsigned row = (unsigned)((n * 16 + ri) * 128);
    adF[n][0] = kv0 + row + offk0;
    adF[n][1] = kv0 + row + offk1;
  }
  const unsigned ps0 = ldsoff(&Ps[0][0][0]) + (unsigned)(w * 2048 + ri * 128);
  unsigned adPr[2] = {ps0 + offk0, ps0 + offk1};
  char* pwb = (char*)&Ps[0][0][0] + w * 2048 + ri * 128;

  bf16x8 qf[2];
  qf[0] = *(const bf16x8*)(qp + (size_t)(q0 + ri) * 64 + kg * 8);
  qf[1] = *(const bf16x8*)(qp + (size_t)(q0 + ri) * 64 + 32 + kg * 8);

  bf16x8 ones;
#pragma unroll
  for (int e = 0; e < 8; ++e) ones[e] = (short)0x3F80;  // bf16 1.0

  f32x4 oacc[4] = {};
  f32x4 lacc = {};
  float mrun = -1e30f;

#define ASTAGE(T, D) { \
    gload_lds16((const char*)(kp + (size_t)((T) * 64 + c0 * 8 + r8) * 64) + cb, \
                (char*)KV + (D) * 16384 + c0 * 1024); \
    gload_lds16((const char*)(kp + (size_t)((T) * 64 + c1 * 8 + r8) * 64) + cb, \
                (char*)KV + (D) * 16384 + c1 * 1024); \
    gload_lds16((const char*)(vp + (size_t)(c0 * 8 + r8) * 1024 + (T) * 64) + cb, \
                (char*)KV + (D) * 16384 + 8192 + c0 * 1024); \
    gload_lds16((const char*)(vp + (size_t)(c1 * 8 + r8) * 1024 + (T) * 64) + cb, \
                (char*)KV + (D) * 16384 + 8192 + c1 * 1024); }

  ASTAGE(0, 0);
  VM0;
  __syncthreads();

  for (int t = 0; t < 16; ++t) {
    const int cur = t & 1;
    if (t < 15) ASTAGE(t + 1, cur ^ 1);  // flies across the whole tile
    const unsigned bo = (unsigned)(cur * 16384);

    bf16x8 kf[2][4];
#pragma unroll
    for (int n = 0; n < 4; ++n) {
      DSRO(kf[0][n], adF[n][0] + bo, 0);
      DSRO(kf[1][n], adF[n][1] + bo, 0);
    }
    LGKM0; SCHED0;
    f32x4 sac[4] = {};
#pragma unroll
    for (int n = 0; n < 4; ++n) {
      sac[n] = __builtin_amdgcn_mfma_f32_16x16x32_bf16(kf[0][n], qf[0], sac[n], 0, 0, 0);
      sac[n] = __builtin_amdgcn_mfma_f32_16x16x32_bf16(kf[1][n], qf[1], sac[n], 0, 0, 0);
    }

    // lane-local max over this lane's 16 scores (keys n*16+kg*4+r, query ri)
    float mx[4];
#pragma unroll
    for (int n = 0; n < 4; ++n)
      mx[n] = fmaxf(fmaxf(sac[n][0], sac[n][1]), fmaxf(sac[n][2], sac[n][3]));
    float mt16 = fmaxf(fmaxf(mx[0], mx[1]), fmaxf(mx[2], mx[3]));
    if (!__all(mt16 - mrun <= 8.f)) {  // lazy defer-max (T13)
      float mrow = fmaxf(mt16, __shfl_xor(mt16, 16));
      mrow = fmaxf(mrow, __shfl_xor(mrow, 32));
      float mnew = fmaxf(mrun, mrow);
      float corr = exp2f(mrun - mnew);
      mrun = mnew;
      float cr[4];
#pragma unroll
      for (int r = 0; r < 4; ++r) cr[r] = __shfl(corr, kg * 4 + r);
#pragma unroll
      for (int n = 0; n < 4; ++n) {
        oacc[n][0] *= cr[0]; oacc[n][1] *= cr[1];
        oacc[n][2] *= cr[2]; oacc[n][3] *= cr[3];
      }
      lacc[0] *= cr[0]; lacc[1] *= cr[1]; lacc[2] *= cr[2]; lacc[3] *= cr[3];
    }
    // p = exp2(s - m); row-sum handled by the ones-MFMA below (no VALU sum)
#pragma unroll
    for (int n = 0; n < 4; ++n) {
      float p0 = exp2f(sac[n][0] - mrun);
      float p1 = exp2f(sac[n][1] - mrun);
      float p2 = exp2f(sac[n][2] - mrun);
      float p3 = exp2f(sac[n][3] - mrun);
      ushort4 pk;
      pk.x = f2bfu(p0); pk.y = f2bfu(p1);
      pk.z = f2bfu(p2); pk.w = f2bfu(p3);
      *(ushort4*)(pwb + (((n * 32 + kg * 8)) ^ (int)rsw)) = pk;
    }
    LGKM0;

    bf16x8 pf[2], vf[2][4];
    DSRO(pf[0], adPr[0], 0);
    DSRO(pf[1], adPr[1], 0);
#pragma unroll
    for (int n = 0; n < 4; ++n) {
      DSRO(vf[0][n], adF[n][0] + bo, 8192);
      DSRO(vf[1][n], adF[n][1] + bo, 8192);
    }
    LGKM0; SCHED0;
#pragma unroll
    for (int n = 0; n < 4; ++n) {
      oacc[n] = __builtin_amdgcn_mfma_f32_16x16x32_bf16(pf[0], vf[0][n], oacc[n], 0, 0, 0);
      oacc[n] = __builtin_amdgcn_mfma_f32_16x16x32_bf16(pf[1], vf[1][n], oacc[n], 0, 0, 0);
    }
    // l-sum on the matrix pipe: lacc[r] = sum_k P[query kg*4+r][k]
    lacc = __builtin_amdgcn_mfma_f32_16x16x32_bf16(pf[0], ones, lacc, 0, 0, 0);
    lacc = __builtin_amdgcn_mfma_f32_16x16x32_bf16(pf[1], ones, lacc, 0, 0, 0);
    if (t < 15) {
      VM0;
      __syncthreads();
    }
  }

  float ivr[4];
#pragma unroll
  for (int r = 0; r < 4; ++r) ivr[r] = 1.f / lacc[r];
#pragma unroll
  for (int r = 0; r < 4; ++r) {
    int s = q0 + kg * 4 + r;
    size_t base = ((size_t)(bb * 1024 + s)) * 1024 + hh * 64;
#pragma unroll
    for (int n = 0; n < 4; ++n)
      Ob[base + n * 16 + ri] = __float2bfloat16(oacc[n][r] * ivr[r]);
  }
#undef ASTAGE
}

// ---------------- fused residual + LayerNorm ----------------
__global__ __launch_bounds__(256) void ln_kernel(
    const float* __restrict__ a, const float* __restrict__ b,
    const float* __restrict__ gamma, const float* __restrict__ beta,
    float* __restrict__ out_f32, bf16* __restrict__ out_bf16) {
  int row = blockIdx.x;
  int tid = threadIdx.x;
  float4 av = ((const float4*)(a + (size_t)row * 1024))[tid];
  float4 bv = ((const float4*)(b + (size_t)row * 1024))[tid];
  float4 z;
  z.x = av.x + bv.x; z.y = av.y + bv.y; z.z = av.z + bv.z; z.w = av.w + bv.w;
  float s = z.x + z.y + z.z + z.w;
  float ss = z.x * z.x + z.y * z.y + z.z * z.z + z.w * z.w;
#pragma unroll
  for (int o = 32; o >= 1; o >>= 1) { s += __shfl_xor(s, o); ss += __shfl_xor(ss, o); }
  __shared__ float red[8];
  int wid = tid >> 6;
  if ((tid & 63) == 0) { red[wid] = s; red[4 + wid] = ss; }
  __syncthreads();
  s = red[0] + red[1] + red[2] + red[3];
  ss = red[4] + red[5] + red[6] + red[7];
  float mean = s * (1.f / 1024.f);
  float var = ss * (1.f / 1024.f) - mean * mean;
  var = var > 0.f ? var : 0.f;
  float inv = 1.f / (sqrtf(var) + EPS_LN);
  float4 g = ((const float4*)gamma)[tid];
  float4 be = ((const float4*)beta)[tid];
  float4 y;
  y.x = (z.x - mean) * inv * g.x + be.x;
  y.y = (z.y - mean) * inv * g.y + be.y;
  y.z = (z.z - mean) * inv * g.z + be.z;
  y.w = (z.w - mean) * inv * g.w + be.w;
  ((float4*)(out_f32 + (size_t)row * 1024))[tid] = y;
  if (out_bf16) {
    ushort4 o;
    o.x = f2bfu(y.x); o.y = f2bfu(y.y); o.z = f2bfu(y.z); o.w = f2bfu(y.w);
    ((ushort4*)(out_bf16 + (size_t)row * 1024))[tid] = o;
  }
}

// ---------------- launch ----------------
extern "C" void kernel_launch(void* const* d_in, const int* in_sizes, int n_in,
                              void* d_out, int out_size, void* d_ws, size_t ws_size,
                              hipStream_t stream) {
  const float* x = (const float*)d_in[0];
  const float* wq = (const float*)d_in[1];
  const float* bq = (const float*)d_in[2];
  const float* wk = (const float*)d_in[3];
  const float* bk = (const float*)d_in[4];
  const float* wv = (const float*)d_in[5];
  const float* bv = (const float*)d_in[6];
  const float* wo_w = (const float*)d_in[7];
  const float* wo_b = (const float*)d_in[8];
  const float* g1 = (const float*)d_in[9];
  const float* b1 = (const float*)d_in[10];
  const float* ff1w = (const float*)d_in[11];
  const float* ff1b = (const float*)d_in[12];
  const float* ff2w = (const float*)d_in[13];
  const float* ff2b = (const float*)d_in[14];
  const float* g2 = (const float*)d_in[15];
  const float* b2 = (const float*)d_in[16];

  char* ws = (char*)d_ws;
  size_t off = 0;
  auto alloc = [&](size_t bytes) {
    char* p = ws + off;
    off += (bytes + 255) & ~(size_t)255;
    return p;
  };
  bf16* xb = (bf16*)alloc((size_t)NTOK * 1024 * 2);
  bf16* wqkvt = (bf16*)alloc((size_t)3072 * 1024 * 2);
  bf16* wot = (bf16*)alloc((size_t)1024 * 1024 * 2);
  bf16* ff1t = (bf16*)alloc((size_t)2048 * 1024 * 2);
  bf16* ff2t = (bf16*)alloc((size_t)1024 * 2048 * 2);
  float* qkvbias = (float*)alloc(3072 * 4);
  bf16* qbuf = (bf16*)alloc((size_t)64 * 1024 * 64 * 2);
  bf16* kbuf = (bf16*)alloc((size_t)64 * 1024 * 64 * 2);
  bf16* vbuf = (bf16*)alloc((size_t)64 * 1024 * 64 * 2);
  bf16* vtb = (bf16*)alloc((size_t)64 * 64 * 1024 * 2);
  bf16* attnb = (bf16*)alloc((size_t)NTOK * 1024 * 2);
  float* proj = (float*)alloc((size_t)NTOK * 1024 * 4);
  bf16* hb = (bf16*)alloc((size_t)NTOK * 1024 * 2);
  bf16* ff1o = qbuf;            // reuse q+k region (dead after attention)
  float* hbuf = (float*)d_out;  // f32 h scratch (fully rewritten by LN2)

  // prep
  cvt_bf16_kernel<<<(NTOK * 1024 / 4 + 255) / 256, 256, 0, stream>>>(x, xb, NTOK * 1024 / 4);
  transpose_cvt<float><<<dim3(2, 32, 16), 256, 0, stream>>>(wq, wqkvt, 1024, 64);
  transpose_cvt<float><<<dim3(2, 32, 16), 256, 0, stream>>>(wk, wqkvt + 1024 * 1024, 1024, 64);
  transpose_cvt<float><<<dim3(2, 32, 16), 256, 0, stream>>>(wv, wqkvt + 2 * 1024 * 1024, 1024, 64);
  transpose_cvt<float><<<dim3(32, 32, 1), 256, 0, stream>>>(wo_w, wot, 1024, 1024);
  transpose_cvt<float><<<dim3(64, 32, 1), 256, 0, stream>>>(ff1w, ff1t, 1024, 2048);
  transpose_cvt<float><<<dim3(32, 64, 1), 256, 0, stream>>>(ff2w, ff2t, 2048, 1024);
  pack_bias_kernel<<<12, 256, 0, stream>>>(bq, bk, bv, qkvbias);

  // QKV: [4096,1024] x [3072,1024]^T, 768 blocks (3/CU)
  gemm128<<<768, 256, 0, stream>>>(xb, 1024, wqkvt, 1024, 4096, 3072, 1024,
                                   32, 24, qkvbias,
                                   nullptr, nullptr, qbuf, kbuf, vbuf, EPI_QKV);
  // V -> V^T per (b,h)
  transpose_cvt<bf16><<<dim3(2, 32, 64), 256, 0, stream>>>(vbuf, vtb, 1024, 64);
  // attention: 1024 blocks x 4 waves, 16 q-rows/wave (R9 geometry)
  attn_kernel<<<dim3(1024), 256, 0, stream>>>(qbuf, kbuf, vtb, attnb);
  // output projection: 256 blocks
  gemm128<<<256, 256, 0, stream>>>(attnb, 1024, wot, 1024, 4096, 1024, 1024,
                                   32, 8, wo_b,
                                   proj, nullptr, nullptr, nullptr, nullptr, EPI_F32);
  // LN1: h = LN(x + proj)
  ln_kernel<<<4096, 256, 0, stream>>>(x, proj, g1, b1, hbuf, hb);
  // FF1 + ReLU: 512 blocks
  gemm128<<<512, 256, 0, stream>>>(hb, 1024, ff1t, 1024, 4096, 2048, 1024,
                                   32, 16, ff1b,
                                   nullptr, ff1o, nullptr, nullptr, nullptr, EPI_RELU_BF16);
  // FF2: 256 blocks, K=2048
  gemm128<<<256, 256, 0, stream>>>(ff1o, 2048, ff2t, 2048, 4096, 1024, 2048,
                                   32, 8, ff2b,
                                   proj, nullptr, nullptr, nullptr, nullptr, EPI_F32);
  // LN2 -> d_out
  ln_kernel<<<4096, 256, 0, stream>>>(hbuf, proj, g2, b2, (float*)d_out, nullptr);
}

// Round 12
// 167.335 us; speedup vs baseline: 1.0675x; 1.0475x over previous
//
#include <hip/hip_runtime.h>
#include <hip/hip_bf16.h>

typedef __attribute__((ext_vector_type(8))) short bf16x8;
typedef __attribute__((ext_vector_type(4))) float f32x4;
using bf16 = __hip_bfloat16;

#define NTOK 4096
#define EPS_LN 1e-5f
#define QSCL 0.1803368801111244f  // 0.125 * log2(e): softmax in exp2 domain

enum { EPI_F32 = 0, EPI_QKV = 1, EPI_RELU_BF16 = 2, EPI_BF16 = 3 };

#define VM8 asm volatile("s_waitcnt vmcnt(8)" ::: "memory")
#define VM0 asm volatile("s_waitcnt vmcnt(0)" ::: "memory")
#define LGKM0 asm volatile("s_waitcnt lgkmcnt(0)" ::: "memory")
#define SCHED0 __builtin_amdgcn_sched_barrier(0)
#define NOVM
#define DSRO(dst, ad, off) \
  asm volatile("ds_read_b128 %0, %1 offset:" #off : "=v"(dst) : "v"(ad))

__device__ inline void gload_lds16(const void* g, void* l) {
  __builtin_amdgcn_global_load_lds(
      (const __attribute__((address_space(1))) char*)g,
      (__attribute__((address_space(3))) char*)l, 16, 0, 0);
}

__device__ inline unsigned ldsoff(const void* p) {
  return (unsigned)(size_t)(const __attribute__((address_space(3))) char*)p;
}

__device__ inline unsigned short f2bfu(float x) {
  bf16 h = __float2bfloat16(x);
  return __builtin_bit_cast(unsigned short, h);
}
__device__ inline bf16 to_bf16(float v) { return __float2bfloat16(v); }
__device__ inline bf16 to_bf16(bf16 v) { return v; }

// single-op packed f32->bf16 (T12 recipe; no builtin on gfx950)
__device__ inline unsigned cvtpk(float lo, float hi) {
  unsigned r;
  asm volatile("v_cvt_pk_bf16_f32 %0, %1, %2" : "=v"(r) : "v"(lo), "v"(hi));
  return r;
}
__device__ inline float bu2f(unsigned short u) {
  unsigned v = (unsigned)u << 16;
  return __builtin_bit_cast(float, v);
}

// ---------------- prep kernels ----------------

__global__ __launch_bounds__(256) void cvt_bf16_kernel(const float* __restrict__ src,
                                                       bf16* __restrict__ dst, int n4) {
  int i = blockIdx.x * 256 + threadIdx.x;
  if (i >= n4) return;
  float4 v = ((const float4*)src)[i];
  ushort4 o;
  o.x = f2bfu(v.x); o.y = f2bfu(v.y); o.z = f2bfu(v.z); o.w = f2bfu(v.w);
  ((ushort4*)dst)[i] = o;
}

template <typename ST>
__global__ __launch_bounds__(256) void transpose_cvt(const ST* __restrict__ src,
                                                     bf16* __restrict__ dst, int R, int C) {
  __shared__ bf16 tile[32][33];
  int o = blockIdx.z;
  int r0 = blockIdx.y * 32, c0 = blockIdx.x * 32;
  int tx = threadIdx.x & 31, ty = threadIdx.x >> 5;
  const ST* s = src + (size_t)o * R * C;
  bf16* d = dst + (size_t)o * R * C;
#pragma unroll
  for (int i = 0; i < 32; i += 8)
    tile[ty + i][tx] = to_bf16(s[(size_t)(r0 + ty + i) * C + (c0 + tx)]);
  __syncthreads();
#pragma unroll
  for (int i = 0; i < 32; i += 8)
    d[(size_t)(c0 + ty + i) * R + (r0 + tx)] = tile[tx][ty + i];
}

__global__ __launch_bounds__(256) void pack_bias_kernel(const float* __restrict__ bq,
                                                        const float* __restrict__ bk,
                                                        const float* __restrict__ bv,
                                                        float* __restrict__ out) {
  int i = blockIdx.x * 256 + threadIdx.x;
  if (i >= 3072) return;
  out[i] = (i < 1024) ? bq[i] : (i < 2048 ? bk[i - 1024] : bv[i - 2048]);
}

// ---------------- GEMM: 128x128 tile, dbuf, 4 waves, 2 blocks/CU ----------
// (R9-proven structure; +EPI_BF16 output mode)

#define STG(KOFF, DD) { _Pragma("unroll") for (int q = 0; q < 4; ++q) { \
    gload_lds16(gA0 + (KOFF) + (size_t)(q * 32) * lda2, \
                sAb + (DD) * 16384 + q * 4096 + w * 1024); \
    gload_lds16(gB0 + (KOFF) + (size_t)(q * 32) * ldb2, \
                sBb + (DD) * 16384 + q * 4096 + w * 1024); } }

#define TILE(OFFLIT, STG_, VMS) { \
  _Pragma("unroll") for (int i = 0; i < 4; ++i) { \
    DSRO(a[i][0], adA[i][0], OFFLIT); \
    DSRO(a[i][1], adA[i][1], OFFLIT); \
  } \
  _Pragma("unroll") for (int j = 0; j < 4; ++j) { \
    DSRO(b[j][0], adB[j][0], OFFLIT); \
    DSRO(b[j][1], adB[j][1], OFFLIT); \
  } \
  LGKM0; SCHED0; \
  __builtin_amdgcn_s_barrier(); \
  STG_; \
  __builtin_amdgcn_s_setprio(1); \
  _Pragma("unroll") for (int i = 0; i < 4; ++i) \
  _Pragma("unroll") for (int j = 0; j < 4; ++j) \
  _Pragma("unroll") for (int kk = 0; kk < 2; ++kk) \
    acc[i][j] = __builtin_amdgcn_mfma_f32_16x16x32_bf16( \
        a[i][kk], b[j][kk], acc[i][j], 0, 0, 0); \
  __builtin_amdgcn_s_setprio(0); \
  VMS; \
  __builtin_amdgcn_s_barrier(); }

__global__ __launch_bounds__(256, 2) void gemm128(
    const bf16* __restrict__ A, int lda,
    const bf16* __restrict__ Bt, int ldb,
    int M, int N, int K,  // K % 128 == 0
    int nbm, int nbn,
    const float* __restrict__ bias,
    float* __restrict__ Cf, bf16* __restrict__ Cb,
    bf16* __restrict__ Qd, bf16* __restrict__ Kd, bf16* __restrict__ Vd,
    int mode) {
  __shared__ bf16 sA[2][128][64];
  __shared__ bf16 sB[2][128][64];
  const int nwg = nbm * nbn;
  const int orig = blockIdx.x;
  const int wgid = (orig % 8) * (nwg / 8) + orig / 8;  // nwg % 8 == 0
  const int bm = wgid / nbn, bn = wgid % nbn;
  const int tid = threadIdx.x;
  const int w = tid >> 6, lane = tid & 63;
  const int wm = w >> 1, wn = w & 1;
  const int ri = lane & 15, kg = lane >> 4;
  const bf16* Ab = A + (size_t)bm * 128 * lda;
  const bf16* Bb = Bt + (size_t)bn * 128 * ldb;
  const int NT = K / 64;
  const size_t lda2 = (size_t)lda * 2, ldb2 = (size_t)ldb * 2;
  char* sAb = (char*)&sA[0][0][0];
  char* sBb = (char*)&sB[0][0][0];

  unsigned adA[4][2], adB[4][2];
  const unsigned sA0 = ldsoff(sAb), sB0 = ldsoff(sBb);
#pragma unroll
  for (int i = 0; i < 4; ++i) {
    int row = wm * 64 + i * 16 + ri;
    unsigned swz = (unsigned)((row & 7) << 4);
    adA[i][0] = sA0 + row * 128 + ((kg * 16) ^ swz);
    adA[i][1] = sA0 + row * 128 + ((64 + kg * 16) ^ swz);
  }
#pragma unroll
  for (int j = 0; j < 4; ++j) {
    int row = wn * 64 + j * 16 + ri;
    unsigned swz = (unsigned)((row & 7) << 4);
    adB[j][0] = sB0 + row * 128 + ((kg * 16) ^ swz);
    adB[j][1] = sB0 + row * 128 + ((64 + kg * 16) ^ swz);
  }

  const int r0 = tid >> 3;
  const int cb0 = ((tid & 7) * 16) ^ ((r0 & 7) << 4);
  const char* gA0 = (const char*)Ab + (size_t)r0 * lda2 + cb0;
  const char* gB0 = (const char*)Bb + (size_t)r0 * ldb2 + cb0;

  f32x4 acc[4][4] = {};
  bf16x8 a[4][2], b[4][2];

  STG(0, 0) STG(128, 1)
  VM8;
  __builtin_amdgcn_s_barrier();

  const int niter = NT / 2 - 1;
  for (int it = 0; it < niter; ++it) {
    TILE(0,     STG(256, 0), VM8)
    TILE(16384, STG(384, 1), VM8)
    gA0 += 256; gB0 += 256;
  }
  TILE(0,     , VM0)
  TILE(16384, , NOVM)

  const int colbase = bn * 128 + wn * 64 + ri;
  float bv4[4];
#pragma unroll
  for (int nf = 0; nf < 4; ++nf)
    bv4[nf] = bias ? bias[colbase + nf * 16] : 0.f;

  if (mode == EPI_QKV) {
    int col0 = bn * 128 + wn * 64;
    int which = col0 >> 10, hh = (col0 >> 6) & 15;
    bf16* dst = (which == 0) ? Qd : (which == 1) ? Kd : Vd;
    float scl = (which == 0) ? QSCL : 1.0f;
#pragma unroll
    for (int mf = 0; mf < 4; ++mf)
#pragma unroll
      for (int r = 0; r < 4; ++r) {
        int row = bm * 128 + wm * 64 + mf * 16 + kg * 4 + r;
        int b2 = row >> 10, s = row & 1023;
        bf16* o = dst + (((size_t)(b2 * 16 + hh)) * 1024 + s) * 64;
#pragma unroll
        for (int nf = 0; nf < 4; ++nf)
          o[nf * 16 + ri] = __float2bfloat16((acc[mf][nf][r] + bv4[nf]) * scl);
      }
  } else if (mode == EPI_F32) {
#pragma unroll
    for (int mf = 0; mf < 4; ++mf)
#pragma unroll
      for (int r = 0; r < 4; ++r) {
        int row = bm * 128 + wm * 64 + mf * 16 + kg * 4 + r;
        float* o = Cf + (size_t)row * N + colbase;
#pragma unroll
        for (int nf = 0; nf < 4; ++nf) o[nf * 16] = acc[mf][nf][r] + bv4[nf];
      }
  } else if (mode == EPI_RELU_BF16) {
#pragma unroll
    for (int mf = 0; mf < 4; ++mf)
#pragma unroll
      for (int r = 0; r < 4; ++r) {
        int row = bm * 128 + wm * 64 + mf * 16 + kg * 4 + r;
        bf16* o = Cb + (size_t)row * N + colbase;
#pragma unroll
        for (int nf = 0; nf < 4; ++nf) {
          float v = acc[mf][nf][r] + bv4[nf];
          o[nf * 16] = __float2bfloat16(v > 0.f ? v : 0.f);
        }
      }
  } else {  // EPI_BF16
#pragma unroll
    for (int mf = 0; mf < 4; ++mf)
#pragma unroll
      for (int r = 0; r < 4; ++r) {
        int row = bm * 128 + wm * 64 + mf * 16 + kg * 4 + r;
        bf16* o = Cb + (size_t)row * N + colbase;
#pragma unroll
        for (int nf = 0; nf < 4; ++nf)
          o[nf * 16] = __float2bfloat16(acc[mf][nf][r] + bv4[nf]);
      }
  }
}

// ---------------- flash attention: cvt_pk P-pack, literal LDS offsets ----------
// R9 geometry: grid 1024 = 64 bh * 16 q-tiles, 4 waves x 16 q-rows, 4 blk/CU.
// t-loop unrolled x2: dbuf selected by ds_read offset literal (0/16384 K,
// 8192/24576 V) — zero per-tile address VALU. P packed via v_cvt_pk_bf16_f32
// (1 op / 2 values vs ~6-op soft RNE). l-sum on matrix pipe (ones-MFMA).
__global__ __launch_bounds__(256, 4) void attn_kernel(
    const bf16* __restrict__ Qb, const bf16* __restrict__ Kb,
    const bf16* __restrict__ Vs, bf16* __restrict__ Ob) {
  __shared__ bf16 KV[2][2][64][64];  // [dbuf][0=K rows=key | 1=V^T rows=d]
  __shared__ bf16 Ps[4][16][64];     // per-wave P [query][key], swizzled
  const int orig = blockIdx.x;
  const int blk = (orig & 7) * 128 + (orig >> 3);  // 1024 % 8 == 0
  const int bh = blk >> 4, qt = blk & 15;
  const int bb = bh >> 4, hh = bh & 15;
  const int tid = threadIdx.x, w = tid >> 6, lane = tid & 63;
  const int ri = lane & 15, kg = lane >> 4, r8 = lane >> 3;
  const int cb = ((lane & 7) * 16) ^ ((r8 & 7) << 4);  // pre-swizzled source
  const unsigned rsw = (unsigned)((ri & 7) << 4);
  const bf16* qp = Qb + (size_t)bh * 65536;
  const bf16* kp = Kb + (size_t)bh * 65536;
  const bf16* vp = Vs + (size_t)bh * 65536;
  const int q0 = qt * 64 + w * 16;
  const int c0 = w * 2, c1 = c0 + 1;

  unsigned offk0 = (unsigned)((kg * 16) ^ (int)rsw);
  unsigned offk1 = (unsigned)((64 + kg * 16) ^ (int)rsw);
  unsigned adF[4][2];
  const unsigned kv0 = ldsoff(&KV[0][0][0][0]);
#pragma unroll
  for (int n = 0; n < 4; ++n) {
    unsigned row = (unsigned)((n * 16 + ri) * 128);
    adF[n][0] = kv0 + row + offk0;
    adF[n][1] = kv0 + row + offk1;
  }
  const unsigned ps0 = ldsoff(&Ps[0][0][0]) + (unsigned)(w * 2048 + ri * 128);
  unsigned adPr[2] = {ps0 + offk0, ps0 + offk1};
  char* pwb = (char*)&Ps[0][0][0] + w * 2048 + ri * 128;
  char* adPw[4];
#pragma unroll
  for (int n = 0; n < 4; ++n)
    adPw[n] = pwb + ((n * 32 + kg * 8) ^ (int)rsw);

  bf16x8 qf[2];
  qf[0] = *(const bf16x8*)(qp + (size_t)(q0 + ri) * 64 + kg * 8);
  qf[1] = *(const bf16x8*)(qp + (size_t)(q0 + ri) * 64 + 32 + kg * 8);

  bf16x8 ones;
#pragma unroll
  for (int e = 0; e < 8; ++e) ones[e] = (short)0x3F80;  // bf16 1.0

  f32x4 oacc[4] = {};
  f32x4 lacc = {};
  float mrun = -1e30f;

#define ASTAGE(T, D) { \
    gload_lds16((const char*)(kp + (size_t)((T) * 64 + c0 * 8 + r8) * 64) + cb, \
                (char*)KV + (D) * 16384 + c0 * 1024); \
    gload_lds16((const char*)(kp + (size_t)((T) * 64 + c1 * 8 + r8) * 64) + cb, \
                (char*)KV + (D) * 16384 + c1 * 1024); \
    gload_lds16((const char*)(vp + (size_t)(c0 * 8 + r8) * 1024 + (T) * 64) + cb, \
                (char*)KV + (D) * 16384 + 8192 + c0 * 1024); \
    gload_lds16((const char*)(vp + (size_t)(c1 * 8 + r8) * 1024 + (T) * 64) + cb, \
                (char*)KV + (D) * 16384 + 8192 + c1 * 1024); }

#define ATILE(KOFF, VOFF, STG_, ENDSYNC) { \
  bf16x8 kf0[4], kf1[4]; \
  _Pragma("unroll") for (int n = 0; n < 4; ++n) { \
    DSRO(kf0[n], adF[n][0], KOFF); \
    DSRO(kf1[n], adF[n][1], KOFF); \
  } \
  STG_; \
  LGKM0; SCHED0; \
  f32x4 sac[4] = {}; \
  _Pragma("unroll") for (int n = 0; n < 4; ++n) { \
    sac[n] = __builtin_amdgcn_mfma_f32_16x16x32_bf16(kf0[n], qf[0], sac[n], 0, 0, 0); \
    sac[n] = __builtin_amdgcn_mfma_f32_16x16x32_bf16(kf1[n], qf[1], sac[n], 0, 0, 0); \
  } \
  float mx[4]; \
  _Pragma("unroll") for (int n = 0; n < 4; ++n) \
    mx[n] = fmaxf(fmaxf(sac[n][0], sac[n][1]), fmaxf(sac[n][2], sac[n][3])); \
  float mt16 = fmaxf(fmaxf(mx[0], mx[1]), fmaxf(mx[2], mx[3])); \
  if (!__all(mt16 - mrun <= 8.f)) { \
    float mrow = fmaxf(mt16, __shfl_xor(mt16, 16)); \
    mrow = fmaxf(mrow, __shfl_xor(mrow, 32)); \
    float mnew = fmaxf(mrun, mrow); \
    float corr = exp2f(mrun - mnew); \
    mrun = mnew; \
    float cr[4]; \
    _Pragma("unroll") for (int r = 0; r < 4; ++r) cr[r] = __shfl(corr, kg * 4 + r); \
    _Pragma("unroll") for (int n = 0; n < 4; ++n) { \
      oacc[n][0] *= cr[0]; oacc[n][1] *= cr[1]; \
      oacc[n][2] *= cr[2]; oacc[n][3] *= cr[3]; \
    } \
    lacc[0] *= cr[0]; lacc[1] *= cr[1]; lacc[2] *= cr[2]; lacc[3] *= cr[3]; \
  } \
  _Pragma("unroll") for (int n = 0; n < 4; ++n) { \
    uint2 pk; \
    pk.x = cvtpk(exp2f(sac[n][0] - mrun), exp2f(sac[n][1] - mrun)); \
    pk.y = cvtpk(exp2f(sac[n][2] - mrun), exp2f(sac[n][3] - mrun)); \
    *(uint2*)adPw[n] = pk; \
  } \
  LGKM0; \
  bf16x8 pf0, pf1, vf0[4], vf1[4]; \
  DSRO(pf0, adPr[0], 0); \
  DSRO(pf1, adPr[1], 0); \
  _Pragma("unroll") for (int n = 0; n < 4; ++n) { \
    DSRO(vf0[n], adF[n][0], VOFF); \
    DSRO(vf1[n], adF[n][1], VOFF); \
  } \
  LGKM0; SCHED0; \
  _Pragma("unroll") for (int n = 0; n < 4; ++n) { \
    oacc[n] = __builtin_amdgcn_mfma_f32_16x16x32_bf16(pf0, vf0[n], oacc[n], 0, 0, 0); \
    oacc[n] = __builtin_amdgcn_mfma_f32_16x16x32_bf16(pf1, vf1[n], oacc[n], 0, 0, 0); \
  } \
  lacc = __builtin_amdgcn_mfma_f32_16x16x32_bf16(pf0, ones, lacc, 0, 0, 0); \
  lacc = __builtin_amdgcn_mfma_f32_16x16x32_bf16(pf1, ones, lacc, 0, 0, 0); \
  ENDSYNC }

#define SYNCT { VM0; __syncthreads(); }

  ASTAGE(0, 0);
  VM0;
  __syncthreads();

  for (int tt = 0; tt < 7; ++tt) {
    const int t2 = tt * 2;
    ATILE(0,     8192,  ASTAGE(t2 + 1, 1), SYNCT)   // even tile (buf0)
    ATILE(16384, 24576, ASTAGE(t2 + 2, 0), SYNCT)   // odd tile  (buf1)
  }
  ATILE(0,     8192,  ASTAGE(15, 1), SYNCT)         // tile 14
  ATILE(16384, 24576, ,              )              // tile 15

  float ivr[4];
#pragma unroll
  for (int r = 0; r < 4; ++r) ivr[r] = 1.f / lacc[r];
#pragma unroll
  for (int r = 0; r < 4; ++r) {
    int s = q0 + kg * 4 + r;
    size_t base = ((size_t)(bb * 1024 + s)) * 1024 + hh * 64;
#pragma unroll
    for (int n = 0; n < 4; ++n)
      Ob[base + n * 16 + ri] = __float2bfloat16(oacc[n][r] * ivr[r]);
  }
#undef ASTAGE
#undef ATILE
#undef SYNCT
}

// ---------------- fused residual + LayerNorm (bf16+bf16 inputs) ----------------
__global__ __launch_bounds__(256) void ln_bb(
    const bf16* __restrict__ a, const bf16* __restrict__ b,
    const float* __restrict__ gamma, const float* __restrict__ beta,
    float* __restrict__ out_f32, bf16* __restrict__ out_bf16) {
  int row = blockIdx.x;
  int tid = threadIdx.x;
  ushort4 au = ((const ushort4*)(a + (size_t)row * 1024))[tid];
  ushort4 bu = ((const ushort4*)(b + (size_t)row * 1024))[tid];
  float4 z;
  z.x = bu2f(au.x) + bu2f(bu.x);
  z.y = bu2f(au.y) + bu2f(bu.y);
  z.z = bu2f(au.z) + bu2f(bu.z);
  z.w = bu2f(au.w) + bu2f(bu.w);
  float s = z.x + z.y + z.z + z.w;
  float ss = z.x * z.x + z.y * z.y + z.z * z.z + z.w * z.w;
#pragma unroll
  for (int o = 32; o >= 1; o >>= 1) { s += __shfl_xor(s, o); ss += __shfl_xor(ss, o); }
  __shared__ float red[8];
  int wid = tid >> 6;
  if ((tid & 63) == 0) { red[wid] = s; red[4 + wid] = ss; }
  __syncthreads();
  s = red[0] + red[1] + red[2] + red[3];
  ss = red[4] + red[5] + red[6] + red[7];
  float mean = s * (1.f / 1024.f);
  float var = ss * (1.f / 1024.f) - mean * mean;
  var = var > 0.f ? var : 0.f;
  float inv = 1.f / (sqrtf(var) + EPS_LN);
  float4 g = ((const float4*)gamma)[tid];
  float4 be = ((const float4*)beta)[tid];
  float4 y;
  y.x = (z.x - mean) * inv * g.x + be.x;
  y.y = (z.y - mean) * inv * g.y + be.y;
  y.z = (z.z - mean) * inv * g.z + be.z;
  y.w = (z.w - mean) * inv * g.w + be.w;
  ((float4*)(out_f32 + (size_t)row * 1024))[tid] = y;
  ushort4 o;
  o.x = f2bfu(y.x); o.y = f2bfu(y.y); o.z = f2bfu(y.z); o.w = f2bfu(y.w);
  ((ushort4*)(out_bf16 + (size_t)row * 1024))[tid] = o;
}

// ---------------- fused residual + LayerNorm (f32 + bf16 inputs) ----------------
__global__ __launch_bounds__(256) void ln_fb(
    const float* __restrict__ a, const bf16* __restrict__ b,
    const float* __restrict__ gamma, const float* __restrict__ beta,
    float* __restrict__ out_f32) {
  int row = blockIdx.x;
  int tid = threadIdx.x;
  float4 av = ((const float4*)(a + (size_t)row * 1024))[tid];
  ushort4 bu = ((const ushort4*)(b + (size_t)row * 1024))[tid];
  float4 z;
  z.x = av.x + bu2f(bu.x);
  z.y = av.y + bu2f(bu.y);
  z.z = av.z + bu2f(bu.z);
  z.w = av.w + bu2f(bu.w);
  float s = z.x + z.y + z.z + z.w;
  float ss = z.x * z.x + z.y * z.y + z.z * z.z + z.w * z.w;
#pragma unroll
  for (int o = 32; o >= 1; o >>= 1) { s += __shfl_xor(s, o); ss += __shfl_xor(ss, o); }
  __shared__ float red[8];
  int wid = tid >> 6;
  if ((tid & 63) == 0) { red[wid] = s; red[4 + wid] = ss; }
  __syncthreads();
  s = red[0] + red[1] + red[2] + red[3];
  ss = red[4] + red[5] + red[6] + red[7];
  float mean = s * (1.f / 1024.f);
  float var = ss * (1.f / 1024.f) - mean * mean;
  var = var > 0.f ? var : 0.f;
  float inv = 1.f / (sqrtf(var) + EPS_LN);
  float4 g = ((const float4*)gamma)[tid];
  float4 be = ((const float4*)beta)[tid];
  float4 y;
  y.x = (z.x - mean) * inv * g.x + be.x;
  y.y = (z.y - mean) * inv * g.y + be.y;
  y.z = (z.z - mean) * inv * g.z + be.z;
  y.w = (z.w - mean) * inv * g.w + be.w;
  ((float4*)(out_f32 + (size_t)row * 1024))[tid] = y;
}

// ---------------- launch ----------------
extern "C" void kernel_launch(void* const* d_in, const int* in_sizes, int n_in,
                              void* d_out, int out_size, void* d_ws, size_t ws_size,
                              hipStream_t stream) {
  const float* x = (const float*)d_in[0];
  const float* wq = (const float*)d_in[1];
  const float* bq = (const float*)d_in[2];
  const float* wk = (const float*)d_in[3];
  const float* bk = (const float*)d_in[4];
  const float* wv = (const float*)d_in[5];
  const float* bv = (const float*)d_in[6];
  const float* wo_w = (const float*)d_in[7];
  const float* wo_b = (const float*)d_in[8];
  const float* g1 = (const float*)d_in[9];
  const float* b1 = (const float*)d_in[10];
  const float* ff1w = (const float*)d_in[11];
  const float* ff1b = (const float*)d_in[12];
  const float* ff2w = (const float*)d_in[13];
  const float* ff2b = (const float*)d_in[14];
  const float* g2 = (const float*)d_in[15];
  const float* b2 = (const float*)d_in[16];

  char* ws = (char*)d_ws;
  size_t off = 0;
  auto alloc = [&](size_t bytes) {
    char* p = ws + off;
    off += (bytes + 255) & ~(size_t)255;
    return p;
  };
  bf16* xb = (bf16*)alloc((size_t)NTOK * 1024 * 2);
  bf16* wqkvt = (bf16*)alloc((size_t)3072 * 1024 * 2);
  bf16* wot = (bf16*)alloc((size_t)1024 * 1024 * 2);
  bf16* ff1t = (bf16*)alloc((size_t)2048 * 1024 * 2);
  bf16* ff2t = (bf16*)alloc((size_t)1024 * 2048 * 2);
  float* qkvbias = (float*)alloc(3072 * 4);
  bf16* qbuf = (bf16*)alloc((size_t)64 * 1024 * 64 * 2);
  bf16* kbuf = (bf16*)alloc((size_t)64 * 1024 * 64 * 2);
  bf16* vbuf = (bf16*)alloc((size_t)64 * 1024 * 64 * 2);
  bf16* vtb = (bf16*)alloc((size_t)64 * 64 * 1024 * 2);
  bf16* attnb = (bf16*)alloc((size_t)NTOK * 1024 * 2);
  bf16* projb = (bf16*)alloc((size_t)NTOK * 1024 * 2);
  bf16* hb = (bf16*)alloc((size_t)NTOK * 1024 * 2);
  bf16* ff1o = qbuf;            // reuse q+k region (dead after attention)
  float* hbuf = (float*)d_out;  // f32 h scratch (fully rewritten by LN2)

  // prep
  cvt_bf16_kernel<<<(NTOK * 1024 / 4 + 255) / 256, 256, 0, stream>>>(x, xb, NTOK * 1024 / 4);
  transpose_cvt<float><<<dim3(2, 32, 16), 256, 0, stream>>>(wq, wqkvt, 1024, 64);
  transpose_cvt<float><<<dim3(2, 32, 16), 256, 0, stream>>>(wk, wqkvt + 1024 * 1024, 1024, 64);
  transpose_cvt<float><<<dim3(2, 32, 16), 256, 0, stream>>>(wv, wqkvt + 2 * 1024 * 1024, 1024, 64);
  transpose_cvt<float><<<dim3(32, 32, 1), 256, 0, stream>>>(wo_w, wot, 1024, 1024);
  transpose_cvt<float><<<dim3(64, 32, 1), 256, 0, stream>>>(ff1w, ff1t, 1024, 2048);
  transpose_cvt<float><<<dim3(32, 64, 1), 256, 0, stream>>>(ff2w, ff2t, 2048, 1024);
  pack_bias_kernel<<<12, 256, 0, stream>>>(bq, bk, bv, qkvbias);

  // QKV: [4096,1024] x [3072,1024]^T, 768 blocks (3/CU)
  gemm128<<<768, 256, 0, stream>>>(xb, 1024, wqkvt, 1024, 4096, 3072, 1024,
                                   32, 24, qkvbias,
                                   nullptr, nullptr, qbuf, kbuf, vbuf, EPI_QKV);
  // V -> V^T per (b,h)
  transpose_cvt<bf16><<<dim3(2, 32, 64), 256, 0, stream>>>(vbuf, vtb, 1024, 64);
  // attention: 1024 blocks x 4 waves, 16 q-rows/wave
  attn_kernel<<<dim3(1024), 256, 0, stream>>>(qbuf, kbuf, vtb, attnb);
  // output projection: 256 blocks, bf16 out
  gemm128<<<256, 256, 0, stream>>>(attnb, 1024, wot, 1024, 4096, 1024, 1024,
                                   32, 8, wo_b,
                                   nullptr, projb, nullptr, nullptr, nullptr, EPI_BF16);
  // LN1: h = LN(xb + projb) -> hbuf (f32) + hb (bf16)
  ln_bb<<<4096, 256, 0, stream>>>(xb, projb, g1, b1, hbuf, hb);
  // FF1 + ReLU: 512 blocks
  gemm128<<<512, 256, 0, stream>>>(hb, 1024, ff1t, 1024, 4096, 2048, 1024,
                                   32, 16, ff1b,
                                   nullptr, ff1o, nullptr, nullptr, nullptr, EPI_RELU_BF16);
  // FF2: 256 blocks, K=2048, bf16 out
  gemm128<<<256, 256, 0, stream>>>(ff1o, 2048, ff2t, 2048, 4096, 1024, 2048,
                                   32, 8, ff2b,
                                   nullptr, projb, nullptr, nullptr, nullptr, EPI_BF16);
  // LN2 -> d_out
  ln_fb<<<4096, 256, 0, stream>>>(hbuf, projb, g2, b2, (float*)d_out);
}

// Round 13
// 158.340 us; speedup vs baseline: 1.1281x; 1.0568x over previous
//
#include <hip/hip_runtime.h>
#include <hip/hip_bf16.h>

typedef __attribute__((ext_vector_type(8))) short bf16x8;
typedef __attribute__((ext_vector_type(4))) float f32x4;
using bf16 = __hip_bfloat16;

#define NTOK 4096
#define EPS_LN 1e-5f
#define QSCL 0.1803368801111244f  // 0.125 * log2(e): softmax in exp2 domain

enum { EPI_F32 = 0, EPI_QKV = 1, EPI_RELU_BF16 = 2, EPI_BF16 = 3 };

#define VM10 asm volatile("s_waitcnt vmcnt(10)" ::: "memory")
#define VM8 asm volatile("s_waitcnt vmcnt(8)" ::: "memory")
#define VM6 asm volatile("s_waitcnt vmcnt(6)" ::: "memory")
#define VM0 asm volatile("s_waitcnt vmcnt(0)" ::: "memory")
#define LGKM0 asm volatile("s_waitcnt lgkmcnt(0)" ::: "memory")
#define SCHED0 __builtin_amdgcn_sched_barrier(0)
#define NOVM
#define DSRO(dst, ad, off) \
  asm volatile("ds_read_b128 %0, %1 offset:" #off : "=v"(dst) : "v"(ad))

__device__ inline void gload_lds16(const void* g, void* l) {
  __builtin_amdgcn_global_load_lds(
      (const __attribute__((address_space(1))) char*)g,
      (__attribute__((address_space(3))) char*)l, 16, 0, 0);
}

__device__ inline unsigned ldsoff(const void* p) {
  return (unsigned)(size_t)(const __attribute__((address_space(3))) char*)p;
}

__device__ inline unsigned short f2bfu(float x) {
  bf16 h = __float2bfloat16(x);
  return __builtin_bit_cast(unsigned short, h);
}
__device__ inline bf16 to_bf16(float v) { return __float2bfloat16(v); }
__device__ inline bf16 to_bf16(bf16 v) { return v; }

__device__ inline unsigned cvtpk(float lo, float hi) {
  unsigned r;
  asm volatile("v_cvt_pk_bf16_f32 %0, %1, %2" : "=v"(r) : "v"(lo), "v"(hi));
  return r;
}
__device__ inline float bu2f(unsigned short u) {
  unsigned v = (unsigned)u << 16;
  return __builtin_bit_cast(float, v);
}

// ---------------- prep kernels ----------------

__global__ __launch_bounds__(256) void cvt_bf16_kernel(const float* __restrict__ src,
                                                       bf16* __restrict__ dst, int n4) {
  int i = blockIdx.x * 256 + threadIdx.x;
  if (i >= n4) return;
  float4 v = ((const float4*)src)[i];
  ushort4 o;
  o.x = f2bfu(v.x); o.y = f2bfu(v.y); o.z = f2bfu(v.z); o.w = f2bfu(v.w);
  ((ushort4*)dst)[i] = o;
}

template <typename ST>
__global__ __launch_bounds__(256) void transpose_cvt(const ST* __restrict__ src,
                                                     bf16* __restrict__ dst, int R, int C) {
  __shared__ bf16 tile[32][33];
  int o = blockIdx.z;
  int r0 = blockIdx.y * 32, c0 = blockIdx.x * 32;
  int tx = threadIdx.x & 31, ty = threadIdx.x >> 5;
  const ST* s = src + (size_t)o * R * C;
  bf16* d = dst + (size_t)o * R * C;
#pragma unroll
  for (int i = 0; i < 32; i += 8)
    tile[ty + i][tx] = to_bf16(s[(size_t)(r0 + ty + i) * C + (c0 + tx)]);
  __syncthreads();
#pragma unroll
  for (int i = 0; i < 32; i += 8)
    d[(size_t)(c0 + ty + i) * R + (r0 + tx)] = tile[tx][ty + i];
}

__global__ __launch_bounds__(256) void pack_bias_kernel(const float* __restrict__ bq,
                                                        const float* __restrict__ bk,
                                                        const float* __restrict__ bv,
                                                        float* __restrict__ out) {
  int i = blockIdx.x * 256 + threadIdx.x;
  if (i >= 3072) return;
  out[i] = (i < 1024) ? bq[i] : (i < 2048 ? bk[i - 1024] : bv[i - 2048]);
}

// ---------------- gemm192: 128x192 tile for QKV (512 blocks, zero tail) -------
// 4 waves (2m x 2n), per-wave 64x96: acc[4][6], 48 MFMA / 20 ds_read per tile.
// LDS: A 2x16KB + B 2x24KB = 80KB -> 2 blocks/CU (160KB exact).

#define STG192(KOFF, DD) { \
  _Pragma("unroll") for (int q = 0; q < 4; ++q) \
    gload_lds16(gA0 + (KOFF) + (size_t)(q * 32) * lda2, \
                sAb + (DD) * 16384 + q * 4096 + w * 1024); \
  _Pragma("unroll") for (int q = 0; q < 6; ++q) \
    gload_lds16(gB0 + (KOFF) + (size_t)(q * 32) * ldb2, \
                sBb + (DD) * 24576 + q * 4096 + w * 1024); }

#define TILE192(AOFF, BOFF, STG_, VMS) { \
  _Pragma("unroll") for (int i = 0; i < 4; ++i) { \
    DSRO(a[i][0], adA[i][0], AOFF); \
    DSRO(a[i][1], adA[i][1], AOFF); \
  } \
  _Pragma("unroll") for (int j = 0; j < 6; ++j) { \
    DSRO(b[j][0], adB[j][0], BOFF); \
    DSRO(b[j][1], adB[j][1], BOFF); \
  } \
  LGKM0; SCHED0; \
  __builtin_amdgcn_s_barrier(); \
  STG_; \
  __builtin_amdgcn_s_setprio(1); \
  _Pragma("unroll") for (int i = 0; i < 4; ++i) \
  _Pragma("unroll") for (int j = 0; j < 6; ++j) \
  _Pragma("unroll") for (int kk = 0; kk < 2; ++kk) \
    acc[i][j] = __builtin_amdgcn_mfma_f32_16x16x32_bf16( \
        a[i][kk], b[j][kk], acc[i][j], 0, 0, 0); \
  __builtin_amdgcn_s_setprio(0); \
  VMS; \
  __builtin_amdgcn_s_barrier(); }

__global__ __launch_bounds__(256, 2) void gemm192(
    const bf16* __restrict__ A, int lda,
    const bf16* __restrict__ Bt, int ldb, int K,
    int nbm, int nbn,
    const float* __restrict__ bias,
    bf16* __restrict__ Qd, bf16* __restrict__ Kd, bf16* __restrict__ Vd) {
  __shared__ bf16 sA[2][128][64];
  __shared__ bf16 sB[2][192][64];
  const int nwg = nbm * nbn;
  const int orig = blockIdx.x;
  const int wgid = (orig % 8) * (nwg / 8) + orig / 8;
  const int bm = wgid / nbn, bn = wgid % nbn;
  const int tid = threadIdx.x;
  const int w = tid >> 6, lane = tid & 63;
  const int wm = w >> 1, wn = w & 1;
  const int ri = lane & 15, kg = lane >> 4;
  const bf16* Ab = A + (size_t)bm * 128 * lda;
  const bf16* Bb = Bt + (size_t)bn * 192 * ldb;
  const int NT = K / 64;
  const size_t lda2 = (size_t)lda * 2, ldb2 = (size_t)ldb * 2;
  char* sAb = (char*)&sA[0][0][0];
  char* sBb = (char*)&sB[0][0][0];

  unsigned adA[4][2], adB[6][2];
  const unsigned sA0 = ldsoff(sAb), sB0 = ldsoff(sBb);
#pragma unroll
  for (int i = 0; i < 4; ++i) {
    int row = wm * 64 + i * 16 + ri;
    unsigned swz = (unsigned)((row & 7) << 4);
    adA[i][0] = sA0 + row * 128 + ((kg * 16) ^ swz);
    adA[i][1] = sA0 + row * 128 + ((64 + kg * 16) ^ swz);
  }
#pragma unroll
  for (int j = 0; j < 6; ++j) {
    int row = wn * 96 + j * 16 + ri;
    unsigned swz = (unsigned)((row & 7) << 4);
    adB[j][0] = sB0 + row * 128 + ((kg * 16) ^ swz);
    adB[j][1] = sB0 + row * 128 + ((64 + kg * 16) ^ swz);
  }

  const int r0 = tid >> 3;
  const int cb0 = ((tid & 7) * 16) ^ ((r0 & 7) << 4);
  const char* gA0 = (const char*)Ab + (size_t)r0 * lda2 + cb0;
  const char* gB0 = (const char*)Bb + (size_t)r0 * ldb2 + cb0;

  f32x4 acc[4][6] = {};
  bf16x8 a[4][2], b[6][2];

  STG192(0, 0) STG192(128, 1)
  VM10;
  __builtin_amdgcn_s_barrier();

  const int niter = NT / 2 - 1;
  for (int it = 0; it < niter; ++it) {
    TILE192(0,     0,     STG192(256, 0), VM10)
    TILE192(16384, 24576, STG192(384, 1), VM10)
    gA0 += 256; gB0 += 256;
  }
  TILE192(0,     0,     , VM0)
  TILE192(16384, 24576, , NOVM)

  // epilogue: QKV scatter; head/which uniform within each 16-wide nf chunk
#pragma unroll
  for (int nf = 0; nf < 6; ++nf) {
    int col0 = bn * 192 + wn * 96 + nf * 16;
    int which = col0 >> 10;
    int hh = (col0 >> 6) & 15;
    int dk0 = col0 & 63;
    bf16* dst = (which == 0) ? Qd : (which == 1) ? Kd : Vd;
    float scl = (which == 0) ? QSCL : 1.0f;
    float bv = bias[col0 + ri];
#pragma unroll
    for (int mf = 0; mf < 4; ++mf)
#pragma unroll
      for (int r = 0; r < 4; ++r) {
        int row = bm * 128 + wm * 64 + mf * 16 + kg * 4 + r;
        int b2 = row >> 10, s = row & 1023;
        dst[(((size_t)(b2 * 16 + hh)) * 1024 + s) * 64 + dk0 + ri] =
            __float2bfloat16((acc[mf][nf][r] + bv) * scl);
      }
  }
}

// ---------------- gemm64: 128x64 tile for Wo/FF2 (512 blocks, 3/CU) ----------
// 4 waves (2m x 2n), per-wave 64x32: acc[4][2]. LDS 48KB -> 3 blocks/CU.

#define STG64(KOFF, DD) { \
  _Pragma("unroll") for (int q = 0; q < 4; ++q) \
    gload_lds16(gA0 + (KOFF) + (size_t)(q * 32) * lda2, \
                sAb + (DD) * 16384 + q * 4096 + w * 1024); \
  _Pragma("unroll") for (int q = 0; q < 2; ++q) \
    gload_lds16(gB0 + (KOFF) + (size_t)(q * 32) * ldb2, \
                sBb + (DD) * 8192 + q * 4096 + w * 1024); }

#define TILE64(AOFF, BOFF, STG_, VMS) { \
  _Pragma("unroll") for (int i = 0; i < 4; ++i) { \
    DSRO(a[i][0], adA[i][0], AOFF); \
    DSRO(a[i][1], adA[i][1], AOFF); \
  } \
  _Pragma("unroll") for (int j = 0; j < 2; ++j) { \
    DSRO(b[j][0], adB[j][0], BOFF); \
    DSRO(b[j][1], adB[j][1], BOFF); \
  } \
  LGKM0; SCHED0; \
  __builtin_amdgcn_s_barrier(); \
  STG_; \
  __builtin_amdgcn_s_setprio(1); \
  _Pragma("unroll") for (int i = 0; i < 4; ++i) \
  _Pragma("unroll") for (int j = 0; j < 2; ++j) \
  _Pragma("unroll") for (int kk = 0; kk < 2; ++kk) \
    acc[i][j] = __builtin_amdgcn_mfma_f32_16x16x32_bf16( \
        a[i][kk], b[j][kk], acc[i][j], 0, 0, 0); \
  __builtin_amdgcn_s_setprio(0); \
  VMS; \
  __builtin_amdgcn_s_barrier(); }

__global__ __launch_bounds__(256, 3) void gemm64(
    const bf16* __restrict__ A, int lda,
    const bf16* __restrict__ Bt, int ldb,
    int N, int K, int nbm, int nbn,
    const float* __restrict__ bias,
    bf16* __restrict__ Cb) {
  __shared__ bf16 sA[2][128][64];
  __shared__ bf16 sB[2][64][64];
  const int nwg = nbm * nbn;
  const int orig = blockIdx.x;
  const int wgid = (orig % 8) * (nwg / 8) + orig / 8;
  const int bm = wgid / nbn, bn = wgid % nbn;
  const int tid = threadIdx.x;
  const int w = tid >> 6, lane = tid & 63;
  const int wm = w >> 1, wn = w & 1;
  const int ri = lane & 15, kg = lane >> 4;
  const bf16* Ab = A + (size_t)bm * 128 * lda;
  const bf16* Bb = Bt + (size_t)bn * 64 * ldb;
  const int NT = K / 64;
  const size_t lda2 = (size_t)lda * 2, ldb2 = (size_t)ldb * 2;
  char* sAb = (char*)&sA[0][0][0];
  char* sBb = (char*)&sB[0][0][0];

  unsigned adA[4][2], adB[2][2];
  const unsigned sA0 = ldsoff(sAb), sB0 = ldsoff(sBb);
#pragma unroll
  for (int i = 0; i < 4; ++i) {
    int row = wm * 64 + i * 16 + ri;
    unsigned swz = (unsigned)((row & 7) << 4);
    adA[i][0] = sA0 + row * 128 + ((kg * 16) ^ swz);
    adA[i][1] = sA0 + row * 128 + ((64 + kg * 16) ^ swz);
  }
#pragma unroll
  for (int j = 0; j < 2; ++j) {
    int row = wn * 32 + j * 16 + ri;
    unsigned swz = (unsigned)((row & 7) << 4);
    adB[j][0] = sB0 + row * 128 + ((kg * 16) ^ swz);
    adB[j][1] = sB0 + row * 128 + ((64 + kg * 16) ^ swz);
  }

  const int r0 = tid >> 3;
  const int cb0 = ((tid & 7) * 16) ^ ((r0 & 7) << 4);
  const char* gA0 = (const char*)Ab + (size_t)r0 * lda2 + cb0;
  const char* gB0 = (const char*)Bb + (size_t)r0 * ldb2 + cb0;

  f32x4 acc[4][2] = {};
  bf16x8 a[4][2], b[2][2];

  STG64(0, 0) STG64(128, 1)
  VM6;
  __builtin_amdgcn_s_barrier();

  const int niter = NT / 2 - 1;
  for (int it = 0; it < niter; ++it) {
    TILE64(0,     0,    STG64(256, 0), VM6)
    TILE64(16384, 8192, STG64(384, 1), VM6)
    gA0 += 256; gB0 += 256;
  }
  TILE64(0,     0,    , VM0)
  TILE64(16384, 8192, , NOVM)

  const int colbase = bn * 64 + wn * 32 + ri;
  float bv2[2];
#pragma unroll
  for (int nf = 0; nf < 2; ++nf) bv2[nf] = bias[colbase + nf * 16];
#pragma unroll
  for (int mf = 0; mf < 4; ++mf)
#pragma unroll
    for (int r = 0; r < 4; ++r) {
      int row = bm * 128 + wm * 64 + mf * 16 + kg * 4 + r;
      bf16* o = Cb + (size_t)row * N + colbase;
#pragma unroll
      for (int nf = 0; nf < 2; ++nf)
        o[nf * 16] = __float2bfloat16(acc[mf][nf][r] + bv2[nf]);
    }
}

// ---------------- gemm128 (FF1 only: EPI_RELU_BF16) ----------
#define STG(KOFF, DD) { _Pragma("unroll") for (int q = 0; q < 4; ++q) { \
    gload_lds16(gA0 + (KOFF) + (size_t)(q * 32) * lda2, \
                sAb + (DD) * 16384 + q * 4096 + w * 1024); \
    gload_lds16(gB0 + (KOFF) + (size_t)(q * 32) * ldb2, \
                sBb + (DD) * 16384 + q * 4096 + w * 1024); } }

#define TILE(OFFLIT, STG_, VMS) { \
  _Pragma("unroll") for (int i = 0; i < 4; ++i) { \
    DSRO(a[i][0], adA[i][0], OFFLIT); \
    DSRO(a[i][1], adA[i][1], OFFLIT); \
  } \
  _Pragma("unroll") for (int j = 0; j < 4; ++j) { \
    DSRO(b[j][0], adB[j][0], OFFLIT); \
    DSRO(b[j][1], adB[j][1], OFFLIT); \
  } \
  LGKM0; SCHED0; \
  __builtin_amdgcn_s_barrier(); \
  STG_; \
  __builtin_amdgcn_s_setprio(1); \
  _Pragma("unroll") for (int i = 0; i < 4; ++i) \
  _Pragma("unroll") for (int j = 0; j < 4; ++j) \
  _Pragma("unroll") for (int kk = 0; kk < 2; ++kk) \
    acc[i][j] = __builtin_amdgcn_mfma_f32_16x16x32_bf16( \
        a[i][kk], b[j][kk], acc[i][j], 0, 0, 0); \
  __builtin_amdgcn_s_setprio(0); \
  VMS; \
  __builtin_amdgcn_s_barrier(); }

__global__ __launch_bounds__(256, 2) void gemm128(
    const bf16* __restrict__ A, int lda,
    const bf16* __restrict__ Bt, int ldb,
    int N, int K, int nbm, int nbn,
    const float* __restrict__ bias,
    bf16* __restrict__ Cb) {
  __shared__ bf16 sA[2][128][64];
  __shared__ bf16 sB[2][128][64];
  const int nwg = nbm * nbn;
  const int orig = blockIdx.x;
  const int wgid = (orig % 8) * (nwg / 8) + orig / 8;
  const int bm = wgid / nbn, bn = wgid % nbn;
  const int tid = threadIdx.x;
  const int w = tid >> 6, lane = tid & 63;
  const int wm = w >> 1, wn = w & 1;
  const int ri = lane & 15, kg = lane >> 4;
  const bf16* Ab = A + (size_t)bm * 128 * lda;
  const bf16* Bb = Bt + (size_t)bn * 128 * ldb;
  const int NT = K / 64;
  const size_t lda2 = (size_t)lda * 2, ldb2 = (size_t)ldb * 2;
  char* sAb = (char*)&sA[0][0][0];
  char* sBb = (char*)&sB[0][0][0];

  unsigned adA[4][2], adB[4][2];
  const unsigned sA0 = ldsoff(sAb), sB0 = ldsoff(sBb);
#pragma unroll
  for (int i = 0; i < 4; ++i) {
    int row = wm * 64 + i * 16 + ri;
    unsigned swz = (unsigned)((row & 7) << 4);
    adA[i][0] = sA0 + row * 128 + ((kg * 16) ^ swz);
    adA[i][1] = sA0 + row * 128 + ((64 + kg * 16) ^ swz);
  }
#pragma unroll
  for (int j = 0; j < 4; ++j) {
    int row = wn * 64 + j * 16 + ri;
    unsigned swz = (unsigned)((row & 7) << 4);
    adB[j][0] = sB0 + row * 128 + ((kg * 16) ^ swz);
    adB[j][1] = sB0 + row * 128 + ((64 + kg * 16) ^ swz);
  }

  const int r0 = tid >> 3;
  const int cb0 = ((tid & 7) * 16) ^ ((r0 & 7) << 4);
  const char* gA0 = (const char*)Ab + (size_t)r0 * lda2 + cb0;
  const char* gB0 = (const char*)Bb + (size_t)r0 * ldb2 + cb0;

  f32x4 acc[4][4] = {};
  bf16x8 a[4][2], b[4][2];

  STG(0, 0) STG(128, 1)
  VM8;
  __builtin_amdgcn_s_barrier();

  const int niter = NT / 2 - 1;
  for (int it = 0; it < niter; ++it) {
    TILE(0,     STG(256, 0), VM8)
    TILE(16384, STG(384, 1), VM8)
    gA0 += 256; gB0 += 256;
  }
  TILE(0,     , VM0)
  TILE(16384, , NOVM)

  const int colbase = bn * 128 + wn * 64 + ri;
  float bv4[4];
#pragma unroll
  for (int nf = 0; nf < 4; ++nf) bv4[nf] = bias[colbase + nf * 16];
#pragma unroll
  for (int mf = 0; mf < 4; ++mf)
#pragma unroll
    for (int r = 0; r < 4; ++r) {
      int row = bm * 128 + wm * 64 + mf * 16 + kg * 4 + r;
      bf16* o = Cb + (size_t)row * N + colbase;
#pragma unroll
      for (int nf = 0; nf < 4; ++nf) {
        float v = acc[mf][nf][r] + bv4[nf];
        o[nf * 16] = __float2bfloat16(v > 0.f ? v : 0.f);
      }
    }
}

// ---------------- flash attention (R12, unchanged) ----------
__global__ __launch_bounds__(256, 4) void attn_kernel(
    const bf16* __restrict__ Qb, const bf16* __restrict__ Kb,
    const bf16* __restrict__ Vs, bf16* __restrict__ Ob) {
  __shared__ bf16 KV[2][2][64][64];
  __shared__ bf16 Ps[4][16][64];
  const int orig = blockIdx.x;
  const int blk = (orig & 7) * 128 + (orig >> 3);
  const int bh = blk >> 4, qt = blk & 15;
  const int bb = bh >> 4, hh = bh & 15;
  const int tid = threadIdx.x, w = tid >> 6, lane = tid & 63;
  const int ri = lane & 15, kg = lane >> 4, r8 = lane >> 3;
  const int cb = ((lane & 7) * 16) ^ ((r8 & 7) << 4);
  const unsigned rsw = (unsigned)((ri & 7) << 4);
  const bf16* qp = Qb + (size_t)bh * 65536;
  const bf16* kp = Kb + (size_t)bh * 65536;
  const bf16* vp = Vs + (size_t)bh * 65536;
  const int q0 = qt * 64 + w * 16;
  const int c0 = w * 2, c1 = c0 + 1;

  unsigned offk0 = (unsigned)((kg * 16) ^ (int)rsw);
  unsigned offk1 = (unsigned)((64 + kg * 16) ^ (int)rsw);
  unsigned adF[4][2];
  const unsigned kv0 = ldsoff(&KV[0][0][0][0]);
#pragma unroll
  for (int n = 0; n < 4; ++n) {
    unsigned row = (unsigned)((n * 16 + ri) * 128);
    adF[n][0] = kv0 + row + offk0;
    adF[n][1] = kv0 + row + offk1;
  }
  const unsigned ps0 = ldsoff(&Ps[0][0][0]) + (unsigned)(w * 2048 + ri * 128);
  unsigned adPr[2] = {ps0 + offk0, ps0 + offk1};
  char* pwb = (char*)&Ps[0][0][0] + w * 2048 + ri * 128;
  char* adPw[4];
#pragma unroll
  for (int n = 0; n < 4; ++n)
    adPw[n] = pwb + ((n * 32 + kg * 8) ^ (int)rsw);

  bf16x8 qf[2];
  qf[0] = *(const bf16x8*)(qp + (size_t)(q0 + ri) * 64 + kg * 8);
  qf[1] = *(const bf16x8*)(qp + (size_t)(q0 + ri) * 64 + 32 + kg * 8);

  bf16x8 ones;
#pragma unroll
  for (int e = 0; e < 8; ++e) ones[e] = (short)0x3F80;

  f32x4 oacc[4] = {};
  f32x4 lacc = {};
  float mrun = -1e30f;

#define ASTAGE(T, D) { \
    gload_lds16((const char*)(kp + (size_t)((T) * 64 + c0 * 8 + r8) * 64) + cb, \
                (char*)KV + (D) * 16384 + c0 * 1024); \
    gload_lds16((const char*)(kp + (size_t)((T) * 64 + c1 * 8 + r8) * 64) + cb, \
                (char*)KV + (D) * 16384 + c1 * 1024); \
    gload_lds16((const char*)(vp + (size_t)(c0 * 8 + r8) * 1024 + (T) * 64) + cb, \
                (char*)KV + (D) * 16384 + 8192 + c0 * 1024); \
    gload_lds16((const char*)(vp + (size_t)(c1 * 8 + r8) * 1024 + (T) * 64) + cb, \
                (char*)KV + (D) * 16384 + 8192 + c1 * 1024); }

#define ATILE(KOFF, VOFF, STG_, ENDSYNC) { \
  bf16x8 kf0[4], kf1[4]; \
  _Pragma("unroll") for (int n = 0; n < 4; ++n) { \
    DSRO(kf0[n], adF[n][0], KOFF); \
    DSRO(kf1[n], adF[n][1], KOFF); \
  } \
  STG_; \
  LGKM0; SCHED0; \
  f32x4 sac[4] = {}; \
  _Pragma("unroll") for (int n = 0; n < 4; ++n) { \
    sac[n] = __builtin_amdgcn_mfma_f32_16x16x32_bf16(kf0[n], qf[0], sac[n], 0, 0, 0); \
    sac[n] = __builtin_amdgcn_mfma_f32_16x16x32_bf16(kf1[n], qf[1], sac[n], 0, 0, 0); \
  } \
  float mx[4]; \
  _Pragma("unroll") for (int n = 0; n < 4; ++n) \
    mx[n] = fmaxf(fmaxf(sac[n][0], sac[n][1]), fmaxf(sac[n][2], sac[n][3])); \
  float mt16 = fmaxf(fmaxf(mx[0], mx[1]), fmaxf(mx[2], mx[3])); \
  if (!__all(mt16 - mrun <= 8.f)) { \
    float mrow = fmaxf(mt16, __shfl_xor(mt16, 16)); \
    mrow = fmaxf(mrow, __shfl_xor(mrow, 32)); \
    float mnew = fmaxf(mrun, mrow); \
    float corr = exp2f(mrun - mnew); \
    mrun = mnew; \
    float cr[4]; \
    _Pragma("unroll") for (int r = 0; r < 4; ++r) cr[r] = __shfl(corr, kg * 4 + r); \
    _Pragma("unroll") for (int n = 0; n < 4; ++n) { \
      oacc[n][0] *= cr[0]; oacc[n][1] *= cr[1]; \
      oacc[n][2] *= cr[2]; oacc[n][3] *= cr[3]; \
    } \
    lacc[0] *= cr[0]; lacc[1] *= cr[1]; lacc[2] *= cr[2]; lacc[3] *= cr[3]; \
  } \
  _Pragma("unroll") for (int n = 0; n < 4; ++n) { \
    uint2 pk; \
    pk.x = cvtpk(exp2f(sac[n][0] - mrun), exp2f(sac[n][1] - mrun)); \
    pk.y = cvtpk(exp2f(sac[n][2] - mrun), exp2f(sac[n][3] - mrun)); \
    *(uint2*)adPw[n] = pk; \
  } \
  LGKM0; \
  bf16x8 pf0, pf1, vf0[4], vf1[4]; \
  DSRO(pf0, adPr[0], 0); \
  DSRO(pf1, adPr[1], 0); \
  _Pragma("unroll") for (int n = 0; n < 4; ++n) { \
    DSRO(vf0[n], adF[n][0], VOFF); \
    DSRO(vf1[n], adF[n][1], VOFF); \
  } \
  LGKM0; SCHED0; \
  _Pragma("unroll") for (int n = 0; n < 4; ++n) { \
    oacc[n] = __builtin_amdgcn_mfma_f32_16x16x32_bf16(pf0, vf0[n], oacc[n], 0, 0, 0); \
    oacc[n] = __builtin_amdgcn_mfma_f32_16x16x32_bf16(pf1, vf1[n], oacc[n], 0, 0, 0); \
  } \
  lacc = __builtin_amdgcn_mfma_f32_16x16x32_bf16(pf0, ones, lacc, 0, 0, 0); \
  lacc = __builtin_amdgcn_mfma_f32_16x16x32_bf16(pf1, ones, lacc, 0, 0, 0); \
  ENDSYNC }

#define SYNCT { VM0; __syncthreads(); }

  ASTAGE(0, 0);
  VM0;
  __syncthreads();

  for (int tt = 0; tt < 7; ++tt) {
    const int t2 = tt * 2;
    ATILE(0,     8192,  ASTAGE(t2 + 1, 1), SYNCT)
    ATILE(16384, 24576, ASTAGE(t2 + 2, 0), SYNCT)
  }
  ATILE(0,     8192,  ASTAGE(15, 1), SYNCT)
  ATILE(16384, 24576, ,              )

  float ivr[4];
#pragma unroll
  for (int r = 0; r < 4; ++r) ivr[r] = 1.f / lacc[r];
#pragma unroll
  for (int r = 0; r < 4; ++r) {
    int s = q0 + kg * 4 + r;
    size_t base = ((size_t)(bb * 1024 + s)) * 1024 + hh * 64;
#pragma unroll
    for (int n = 0; n < 4; ++n)
      Ob[base + n * 16 + ri] = __float2bfloat16(oacc[n][r] * ivr[r]);
  }
#undef ASTAGE
#undef ATILE
#undef SYNCT
}

// ---------------- fused residual + LayerNorm (bf16 in; bf16 and/or f32 out) ---
__global__ __launch_bounds__(256) void ln_bb(
    const bf16* __restrict__ a, const bf16* __restrict__ b,
    const float* __restrict__ gamma, const float* __restrict__ beta,
    float* __restrict__ out_f32, bf16* __restrict__ out_bf16) {
  int row = blockIdx.x;
  int tid = threadIdx.x;
  ushort4 au = ((const ushort4*)(a + (size_t)row * 1024))[tid];
  ushort4 bu = ((const ushort4*)(b + (size_t)row * 1024))[tid];
  float4 z;
  z.x = bu2f(au.x) + bu2f(bu.x);
  z.y = bu2f(au.y) + bu2f(bu.y);
  z.z = bu2f(au.z) + bu2f(bu.z);
  z.w = bu2f(au.w) + bu2f(bu.w);
  float s = z.x + z.y + z.z + z.w;
  float ss = z.x * z.x + z.y * z.y + z.z * z.z + z.w * z.w;
#pragma unroll
  for (int o = 32; o >= 1; o >>= 1) { s += __shfl_xor(s, o); ss += __shfl_xor(ss, o); }
  __shared__ float red[8];
  int wid = tid >> 6;
  if ((tid & 63) == 0) { red[wid] = s; red[4 + wid] = ss; }
  __syncthreads();
  s = red[0] + red[1] + red[2] + red[3];
  ss = red[4] + red[5] + red[6] + red[7];
  float mean = s * (1.f / 1024.f);
  float var = ss * (1.f / 1024.f) - mean * mean;
  var = var > 0.f ? var : 0.f;
  float inv = 1.f / (sqrtf(var) + EPS_LN);
  float4 g = ((const float4*)gamma)[tid];
  float4 be = ((const float4*)beta)[tid];
  float4 y;
  y.x = (z.x - mean) * inv * g.x + be.x;
  y.y = (z.y - mean) * inv * g.y + be.y;
  y.z = (z.z - mean) * inv * g.z + be.z;
  y.w = (z.w - mean) * inv * g.w + be.w;
  if (out_f32)
    ((float4*)(out_f32 + (size_t)row * 1024))[tid] = y;
  if (out_bf16) {
    ushort4 o;
    o.x = f2bfu(y.x); o.y = f2bfu(y.y); o.z = f2bfu(y.z); o.w = f2bfu(y.w);
    ((ushort4*)(out_bf16 + (size_t)row * 1024))[tid] = o;
  }
}

// ---------------- launch ----------------
extern "C" void kernel_launch(void* const* d_in, const int* in_sizes, int n_in,
                              void* d_out, int out_size, void* d_ws, size_t ws_size,
                              hipStream_t stream) {
  const float* x = (const float*)d_in[0];
  const float* wq = (const float*)d_in[1];
  const float* bq = (const float*)d_in[2];
  const float* wk = (const float*)d_in[3];
  const float* bk = (const float*)d_in[4];
  const float* wv = (const float*)d_in[5];
  const float* bv = (const float*)d_in[6];
  const float* wo_w = (const float*)d_in[7];
  const float* wo_b = (const float*)d_in[8];
  const float* g1 = (const float*)d_in[9];
  const float* b1 = (const float*)d_in[10];
  const float* ff1w = (const float*)d_in[11];
  const float* ff1b = (const float*)d_in[12];
  const float* ff2w = (const float*)d_in[13];
  const float* ff2b = (const float*)d_in[14];
  const float* g2 = (const float*)d_in[15];
  const float* b2 = (const float*)d_in[16];

  char* ws = (char*)d_ws;
  size_t off = 0;
  auto alloc = [&](size_t bytes) {
    char* p = ws + off;
    off += (bytes + 255) & ~(size_t)255;
    return p;
  };
  bf16* xb = (bf16*)alloc((size_t)NTOK * 1024 * 2);
  bf16* wqkvt = (bf16*)alloc((size_t)3072 * 1024 * 2);
  bf16* wot = (bf16*)alloc((size_t)1024 * 1024 * 2);
  bf16* ff1t = (bf16*)alloc((size_t)2048 * 1024 * 2);
  bf16* ff2t = (bf16*)alloc((size_t)1024 * 2048 * 2);
  float* qkvbias = (float*)alloc(3072 * 4);
  bf16* qbuf = (bf16*)alloc((size_t)64 * 1024 * 64 * 2);
  bf16* kbuf = (bf16*)alloc((size_t)64 * 1024 * 64 * 2);
  bf16* vbuf = (bf16*)alloc((size_t)64 * 1024 * 64 * 2);
  bf16* vtb = (bf16*)alloc((size_t)64 * 64 * 1024 * 2);
  bf16* attnb = (bf16*)alloc((size_t)NTOK * 1024 * 2);
  bf16* projb = (bf16*)alloc((size_t)NTOK * 1024 * 2);
  bf16* hb = (bf16*)alloc((size_t)NTOK * 1024 * 2);
  bf16* ff1o = qbuf;  // reuse q+k region (dead after attention)

  // prep
  cvt_bf16_kernel<<<(NTOK * 1024 / 4 + 255) / 256, 256, 0, stream>>>(x, xb, NTOK * 1024 / 4);
  transpose_cvt<float><<<dim3(2, 32, 16), 256, 0, stream>>>(wq, wqkvt, 1024, 64);
  transpose_cvt<float><<<dim3(2, 32, 16), 256, 0, stream>>>(wk, wqkvt + 1024 * 1024, 1024, 64);
  transpose_cvt<float><<<dim3(2, 32, 16), 256, 0, stream>>>(wv, wqkvt + 2 * 1024 * 1024, 1024, 64);
  transpose_cvt<float><<<dim3(32, 32, 1), 256, 0, stream>>>(wo_w, wot, 1024, 1024);
  transpose_cvt<float><<<dim3(64, 32, 1), 256, 0, stream>>>(ff1w, ff1t, 1024, 2048);
  transpose_cvt<float><<<dim3(32, 64, 1), 256, 0, stream>>>(ff2w, ff2t, 2048, 1024);
  pack_bias_kernel<<<12, 256, 0, stream>>>(bq, bk, bv, qkvbias);

  // QKV: 128x192 tiles -> 512 blocks (zero tail)
  gemm192<<<512, 256, 0, stream>>>(xb, 1024, wqkvt, 1024, 1024, 32, 16, qkvbias,
                                   qbuf, kbuf, vbuf);
  // V -> V^T per (b,h)
  transpose_cvt<bf16><<<dim3(2, 32, 64), 256, 0, stream>>>(vbuf, vtb, 1024, 64);
  // attention
  attn_kernel<<<dim3(1024), 256, 0, stream>>>(qbuf, kbuf, vtb, attnb);
  // Wo: 128x64 tiles -> 512 blocks, 3/CU
  gemm64<<<512, 256, 0, stream>>>(attnb, 1024, wot, 1024, 1024, 1024, 32, 16,
                                  wo_b, projb);
  // LN1: h = LN(xb + projb) -> hb (bf16 only)
  ln_bb<<<4096, 256, 0, stream>>>(xb, projb, g1, b1, nullptr, hb);
  // FF1 + ReLU: 128x128, 512 blocks (exact fill)
  gemm128<<<512, 256, 0, stream>>>(hb, 1024, ff1t, 1024, 2048, 1024, 32, 16,
                                   ff1b, ff1o);
  // FF2: 128x64 tiles, K=2048 -> 512 blocks
  gemm64<<<512, 256, 0, stream>>>(ff1o, 2048, ff2t, 2048, 1024, 2048, 32, 16,
                                  ff2b, projb);
  // LN2: out = LN(hb + projb) -> d_out (f32)
  ln_bb<<<4096, 256, 0, stream>>>(hb, projb, g2, b2, (float*)d_out, nullptr);
}